// Round 14
// baseline (3038.223 us; speedup 1.0000x reference)
//
#include <hip/hip_runtime.h>
#include <hip/hip_bf16.h>

#define NN 50000
#define NE 800000
#define H 128
#define NBLK 196   // (NN+255)/256

typedef __hip_bfloat16 bf16;
typedef __attribute__((ext_vector_type(8))) short short8v;
typedef __attribute__((ext_vector_type(4))) float f32x4;

static __device__ __forceinline__ unsigned short f2bf_bits(float x) {
  union { __hip_bfloat16 b; unsigned short u; } cv;
  cv.b = __float2bfloat16(x);
  return cv.u;
}

// ---------------------------------------------------------------------------
// Sort-by-dst build
// ---------------------------------------------------------------------------
__global__ __launch_bounds__(256) void zero_counts_kernel(int* __restrict__ counts) {
  int i = blockIdx.x * 256 + threadIdx.x;
  if (i < NN) counts[i] = 0;
}

__global__ __launch_bounds__(256) void hist_kernel(const int* __restrict__ dstI,
                                                   int* __restrict__ counts) {
  int e = blockIdx.x * 256 + threadIdx.x;
  if (e < NE) atomicAdd(&counts[dstI[e]], 1);
}

// hierarchical scan: 1) per-block sums  2) scan sums  3) apply
__global__ __launch_bounds__(256) void scan1_kernel(const int* __restrict__ counts,
                                                    int* __restrict__ bsum) {
  __shared__ int sdata[256];
  int i = blockIdx.x * 256 + threadIdx.x;
  sdata[threadIdx.x] = (i < NN) ? counts[i] : 0;
  __syncthreads();
  for (int off = 128; off > 0; off >>= 1) {
    if (threadIdx.x < off) sdata[threadIdx.x] += sdata[threadIdx.x + off];
    __syncthreads();
  }
  if (threadIdx.x == 0) bsum[blockIdx.x] = sdata[0];
}

__global__ __launch_bounds__(256) void scan2_kernel(int* __restrict__ bsum) {
  __shared__ int sdata[256];
  const int t = threadIdx.x;
  int v = (t < NBLK) ? bsum[t] : 0;
  sdata[t] = v;
  __syncthreads();
  #pragma unroll
  for (int off = 1; off < 256; off <<= 1) {
    int x = (t >= off) ? sdata[t - off] : 0;
    __syncthreads();
    sdata[t] += x;
    __syncthreads();
  }
  if (t < NBLK) bsum[t] = sdata[t] - v;   // exclusive
}

__global__ __launch_bounds__(256) void scan3_kernel(const int* __restrict__ counts,
                                                    const int* __restrict__ bsum,
                                                    int* __restrict__ cursor) {
  __shared__ int sdata[256];
  const int t = threadIdx.x;
  int i = blockIdx.x * 256 + t;
  int v = (i < NN) ? counts[i] : 0;
  sdata[t] = v;
  __syncthreads();
  #pragma unroll
  for (int off = 1; off < 256; off <<= 1) {
    int x = (t >= off) ? sdata[t - off] : 0;
    __syncthreads();
    sdata[t] += x;
    __syncthreads();
  }
  if (i < NN) cursor[i] = bsum[blockIdx.x] + sdata[t] - v;
}

__global__ __launch_bounds__(256) void scatter_kernel(
    const float* __restrict__ ea, const int* __restrict__ srcI, const int* __restrict__ dstI,
    int* __restrict__ cursor, bf16* __restrict__ eap,
    int* __restrict__ srcp, int* __restrict__ dstp) {
  int e = blockIdx.x * 256 + threadIdx.x;
  if (e >= NE) return;
  int d = dstI[e];
  int pos = atomicAdd(&cursor[d], 1);
  srcp[pos] = srcI[e];
  dstp[pos] = d;
  #pragma unroll
  for (int k = 0; k < 7; ++k) eap[(size_t)pos * 7 + k] = __float2bfloat16(ea[(size_t)e * 7 + k]);
}

// ---------------------------------------------------------------------------
// Fused edge weights: W3p[l] = ee_w2 @ W3[l], c3[l] = ee_b2 @ W3[l] + eb[l]
// ---------------------------------------------------------------------------
__global__ __launch_bounds__(256) void fuse_w3_kernel(
    const float* __restrict__ ee_w2, const float* __restrict__ ee_b2,
    const float* __restrict__ mp_ew, const float* __restrict__ mp_eb,
    float* __restrict__ W3p, float* __restrict__ c3)
{
  const int l = blockIdx.x >> 3;
  const int cc = (blockIdx.x & 7) * 16;
  __shared__ float sA[H * H];
  __shared__ float sB[H * 16];
  const float* W3 = mp_ew + (size_t)l * 384 * H + 256 * H;
  for (int i = threadIdx.x; i < H * H; i += 256) sA[i] = ee_w2[i];
  for (int i = threadIdx.x; i < H * 16; i += 256) {
    int k = i >> 4, j = i & 15;
    sB[i] = W3[k * H + cc + j];
  }
  __syncthreads();
  float* out = W3p + (size_t)l * H * H;
  for (int i = threadIdx.x; i < H * 16; i += 256) {
    int r = i >> 4, j = i & 15;
    float acc = 0.f;
    #pragma unroll 8
    for (int k = 0; k < H; ++k) acc += sA[r * H + k] * sB[k * 16 + j];
    out[r * H + cc + j] = acc;
  }
  if (threadIdx.x < 16) {
    int j = threadIdx.x;
    float acc = mp_eb[l * H + cc + j];
    for (int k = 0; k < H; ++k) acc += ee_b2[k] * sB[k * 16 + j];
    c3[l * H + cc + j] = acc;
  }
}

// ---------------------------------------------------------------------------
// Generic repack: [K x 128] f32 row-major -> bf16 MFMA B-fragment order.
// ---------------------------------------------------------------------------
__global__ __launch_bounds__(256) void repack_w_kernel(
    const float* __restrict__ src0, size_t lstride, bf16* __restrict__ dst0, int K)
{
  const int l = blockIdx.x;
  const float* src = src0 + (size_t)l * lstride;
  bf16* dst = dst0 + (size_t)l * K * 128;
  const int nkk = K / 32;
  const int nslots = 8 * nkk * 64;
  for (int idx = threadIdx.x; idx < nslots; idx += 256) {
    int ng = idx / (nkk * 64);
    int rem = idx % (nkk * 64);
    int kk = rem / 64, ln = rem % 64;
    #pragma unroll
    for (int j = 0; j < 8; ++j) {
      int k = kk * 32 + ((ln >> 4) * 8) + j;
      int col = ng * 16 + (ln & 15);
      dst[(size_t)idx * 8 + j] = __float2bfloat16(src[(size_t)k * 128 + col]);
    }
  }
}

// ---------------------------------------------------------------------------
// Node encoder: h = relu(x @ w1 + b1) @ w2 + b2   (10 -> 128 -> 128)
// ---------------------------------------------------------------------------
__global__ __launch_bounds__(256) void node_encoder_kernel(
    const float* __restrict__ in,
    const float* __restrict__ w1, const float* __restrict__ b1,
    const float* __restrict__ w2, const float* __restrict__ b2,
    float* __restrict__ out, int nrows)
{
  __shared__ float sw1[10 * H];
  __shared__ float sw2[H * H];
  __shared__ float sb1[H];
  __shared__ float sb2[H];
  __shared__ float sin_[8][10];
  __shared__ float st[8][H];

  for (int i = threadIdx.x; i < 10 * H; i += 256) sw1[i] = w1[i];
  for (int i = threadIdx.x; i < H * H; i += 256) sw2[i] = w2[i];
  if (threadIdx.x < H) { sb1[threadIdx.x] = b1[threadIdx.x]; sb2[threadIdx.x] = b2[threadIdx.x]; }
  __syncthreads();

  const int c = threadIdx.x & 127;
  const int hf = threadIdx.x >> 7;

  for (long long r0 = (long long)blockIdx.x * 8; r0 < nrows; r0 += (long long)gridDim.x * 8) {
    if (threadIdx.x < 80) {
      int j = threadIdx.x / 10, k = threadIdx.x % 10;
      long long r = r0 + j;
      sin_[j][k] = (r < nrows) ? in[r * 10 + k] : 0.f;
    }
    __syncthreads();
    #pragma unroll
    for (int t = 0; t < 4; ++t) {
      int idx = threadIdx.x + t * 256;
      int j = idx >> 7, k = idx & 127;
      float acc = sb1[k];
      #pragma unroll
      for (int i = 0; i < 10; ++i) acc += sin_[j][i] * sw1[i * H + k];
      st[j][k] = fmaxf(acc, 0.f);
    }
    __syncthreads();
    float a0 = sb2[c], a1 = a0, a2 = a0, a3 = a0;
    #pragma unroll 4
    for (int k4 = 0; k4 < H; k4 += 4) {
      float w0 = sw2[(k4 + 0) * H + c];
      float w1v = sw2[(k4 + 1) * H + c];
      float w2v = sw2[(k4 + 2) * H + c];
      float w3v = sw2[(k4 + 3) * H + c];
      float4 s0 = *(const float4*)&st[hf * 4 + 0][k4];
      float4 s1 = *(const float4*)&st[hf * 4 + 1][k4];
      float4 s2 = *(const float4*)&st[hf * 4 + 2][k4];
      float4 s3 = *(const float4*)&st[hf * 4 + 3][k4];
      a0 += s0.x * w0 + s0.y * w1v + s0.z * w2v + s0.w * w3v;
      a1 += s1.x * w0 + s1.y * w1v + s1.z * w2v + s1.w * w3v;
      a2 += s2.x * w0 + s2.y * w1v + s2.z * w2v + s2.w * w3v;
      a3 += s3.x * w0 + s3.y * w1v + s3.z * w2v + s3.w * w3v;
    }
    float accs[4] = {a0, a1, a2, a3};
    #pragma unroll
    for (int j = 0; j < 4; ++j) {
      long long r = r0 + hf * 4 + j;
      if (r < nrows) out[r * H + c] = accs[j];
    }
    __syncthreads();
  }
}

// ---------------------------------------------------------------------------
// Layer-0 node GEMMs (fp32): A = bf16(h @ W1), B = bf16(h @ W2); zeroes agg.
// ---------------------------------------------------------------------------
__global__ __launch_bounds__(512) void node_AB_kernel(
    const float* __restrict__ h, const float* __restrict__ W1f, const float* __restrict__ W2f,
    bf16* __restrict__ A, bf16* __restrict__ B, float* __restrict__ agg, int nrows)
{
  __shared__ float sw1[H * H];
  __shared__ float sw2[H * H];
  __shared__ float sh[16][H];
  for (int i = threadIdx.x; i < H * H; i += 512) { sw1[i] = W1f[i]; sw2[i] = W2f[i]; }
  __syncthreads();
  const int c = threadIdx.x & 127;
  const int q = threadIdx.x >> 7;
  for (long long r0 = (long long)blockIdx.x * 16; r0 < nrows; r0 += (long long)gridDim.x * 16) {
    #pragma unroll
    for (int t = 0; t < 4; ++t) {
      int idx = threadIdx.x + t * 512;
      int j = idx >> 7, k = idx & 127;
      long long r = r0 + j;
      sh[j][k] = (r < nrows) ? h[r * H + k] : 0.f;
    }
    __syncthreads();
    float aA[4] = {0, 0, 0, 0}, aB[4] = {0, 0, 0, 0};
    #pragma unroll 2
    for (int k4 = 0; k4 < H; k4 += 4) {
      float w10 = sw1[(k4 + 0) * H + c], w11 = sw1[(k4 + 1) * H + c];
      float w12 = sw1[(k4 + 2) * H + c], w13 = sw1[(k4 + 3) * H + c];
      float w20 = sw2[(k4 + 0) * H + c], w21 = sw2[(k4 + 1) * H + c];
      float w22 = sw2[(k4 + 2) * H + c], w23 = sw2[(k4 + 3) * H + c];
      #pragma unroll
      for (int j = 0; j < 4; ++j) {
        float4 s = *(const float4*)&sh[q * 4 + j][k4];
        aA[j] += s.x * w10 + s.y * w11 + s.z * w12 + s.w * w13;
        aB[j] += s.x * w20 + s.y * w21 + s.z * w22 + s.w * w23;
      }
    }
    #pragma unroll
    for (int j = 0; j < 4; ++j) {
      long long r = r0 + q * 4 + j;
      if (r < nrows) {
        A[r * H + c] = __float2bfloat16(aA[j]);
        B[r * H + c] = __float2bfloat16(aB[j]);
        agg[r * H + c] = 0.f;
      }
    }
    __syncthreads();
  }
}

// ---------------------------------------------------------------------------
// Edge kernel (ownership, no global atomics on the main path).
// dst-sorted => each dst's edges are ONE contiguous run. Tile t (64-slot
// window at L=t*64) OWNS all runs starting in [L, L+64). Max degree << 64
// => owned runs end before L+128, so two masked 64-edge passes cover them.
// Per-run partials are register-reduced, combined across waves/passes via
// shallow LDS atomics into sagg[16][128], then agg rows written with PLAIN
// STORES (agg pre-zeroed; each dst has exactly one owner). li>=16 fallback:
// device atomicAdd (probability ~0, correctness only).
// ---------------------------------------------------------------------------
__global__ __launch_bounds__(512) void edge_mfma_own(
    const bf16* __restrict__ eap,
    const int* __restrict__ srcp, const int* __restrict__ dstp,
    const bf16* __restrict__ A, const bf16* __restrict__ B,
    const float* __restrict__ ew1, const float* __restrict__ eb1,
    const bf16* __restrict__ W3b, const float* __restrict__ c3,
    float* __restrict__ agg, int nE)
{
  __shared__ int sdidx[129];              // [0]=dst[L-1] (or -1), [1+j]=dst[L+j] j<128
  __shared__ int sssrc[128];
  __shared__ unsigned long long sb[2];
  __shared__ int sgdst[64];
  __shared__ unsigned short seaP[64][40]; // 5KB, K-padded GEMM1 A (cols 7..39 zero)
  __shared__ unsigned int shid[64 * 64];  // 16KB bf16 [64][128] swizzled
  __shared__ bf16 sAld[64][136];          // 17KB staged A rows
  __shared__ float sagg[16 * 128];        // 8KB per-run accumulators

  const int t = threadIdx.x;
  const int lane = t & 63;
  const int wid = t >> 6;
  const int hm = wid >> 2;
  const int colbase = (wid & 3) * 32;
  const long long L = (long long)blockIdx.x * 64;

  for (int i = t; i < 64 * 40; i += 512) ((unsigned short*)seaP)[i] = 0;
  for (int i = t; i < 16 * 128; i += 512) sagg[i] = 0.f;
  if (t < 128) {
    long long s = L + t;
    sdidx[1 + t] = (s < nE) ? dstp[s] : -1;
    sssrc[t] = (s < nE) ? srcp[s] : 0;
  }
  if (t == 128) sdidx[0] = (L > 0) ? dstp[L - 1] : -1;

  // GEMM2 B-fragments + c3
  short8v bfrag[2][4];
  float c3v[2];
  #pragma unroll
  for (int n = 0; n < 2; ++n) {
    c3v[n] = c3[colbase + n * 16 + (lane & 15)];
    int ng = (colbase >> 4) + n;
    #pragma unroll
    for (int kk = 0; kk < 4; ++kk)
      bfrag[n][kk] = *(const short8v*)(W3b + ((size_t)(ng * 4 + kk) * 64 + lane) * 8);
  }
  // GEMM1 B-fragments (ew1 K-padded) + bias
  short8v bew[2];
  float eb1v[2];
  #pragma unroll
  for (int n = 0; n < 2; ++n) {
    int col = colbase + n * 16 + (lane & 15);
    eb1v[n] = eb1[col];
    #pragma unroll
    for (int j = 0; j < 8; ++j) {
      int k = (lane >> 4) * 8 + j;
      bew[n][j] = (short)((k < 7) ? f2bf_bits(ew1[k * H + col]) : 0);
    }
  }
  __syncthreads();

  // ---- ownership ballots ----
  if (wid == 0) {
    int j = lane;
    bool bnd = sdidx[1 + j] != sdidx[j];
    unsigned long long m = __ballot(bnd);
    if (bnd) sgdst[(int)__popcll(m & ((2ull << j) - 1ull)) - 1] = sdidx[1 + j];
    if (lane == 0) sb[0] = m;
  } else if (wid == 1) {
    int j = 64 + lane;
    bool bnd = sdidx[1 + j] != sdidx[j];
    unsigned long long m = __ballot(bnd);
    if (lane == 0) sb[1] = m;
  }
  __syncthreads();
  const unsigned long long b0 = sb[0], b1 = sb[1];
  const int ndst = (int)__popcll(b0);

  const int elA0 = t >> 4;
  const int elA1 = 32 + (t >> 4);
  const int segA = (t & 15) * 8;
  const int col0 = colbase + (lane & 15);
  const int col1 = col0 + 16;

  #pragma unroll 1
  for (int pass = 0; pass < 2; ++pass) {
    if (pass == 1 && (((b1 & 1ull) != 0) || b0 == 0)) break;
    const int base = pass * 64;

    // owned(j) helper values for staging
    // ---- stage seaP (gated by ownership) ----
    if (t < 448) {
      int e = t / 7, k = t % 7;
      int j = base + e;
      bool own;
      if (j < 64) own = (b0 & ((2ull << j) - 1ull)) != 0;
      else        own = ((b1 & ((2ull << (j - 64)) - 1ull)) == 0) && (b0 != 0);
      if (own) seaP[e][k] = ((const unsigned short*)eap)[(L + j) * 7 + k];
    }
    // ---- stage A rows (gated) ----
    {
      int e0i = elA0, j0 = base + e0i;
      bool own0;
      if (j0 < 64) own0 = (b0 & ((2ull << j0) - 1ull)) != 0;
      else         own0 = ((b1 & ((2ull << (j0 - 64)) - 1ull)) == 0) && (b0 != 0);
      if (own0) {
        int s = sssrc[j0];
        *(short8v*)&sAld[e0i][segA] = *(const short8v*)&A[(size_t)s * H + segA];
      }
      int e1i = elA1, j1 = base + e1i;
      bool own1;
      if (j1 < 64) own1 = (b0 & ((2ull << j1) - 1ull)) != 0;
      else         own1 = ((b1 & ((2ull << (j1 - 64)) - 1ull)) == 0) && (b0 != 0);
      if (own1) {
        int s = sssrc[j1];
        *(short8v*)&sAld[e1i][segA] = *(const short8v*)&A[(size_t)s * H + segA];
      }
    }
    __syncthreads();

    // ---- GEMM1: hid = relu(eaP @ ew1P + eb1) ----
    {
      f32x4 h1[2][2];
      const f32x4 z = {0.f, 0.f, 0.f, 0.f};
      h1[0][0] = z; h1[0][1] = z; h1[1][0] = z; h1[1][1] = z;
      #pragma unroll
      for (int m = 0; m < 2; ++m) {
        int row = hm * 32 + m * 16 + (lane & 15);
        short8v afrag = *(const short8v*)((const char*)seaP + row * 80 + (lane >> 4) * 16);
        h1[m][0] = __builtin_amdgcn_mfma_f32_16x16x32_bf16(afrag, bew[0], h1[m][0], 0, 0, 0);
        h1[m][1] = __builtin_amdgcn_mfma_f32_16x16x32_bf16(afrag, bew[1], h1[m][1], 0, 0, 0);
      }
      #pragma unroll
      for (int m = 0; m < 2; ++m) {
        #pragma unroll
        for (int r = 0; r < 4; ++r) {
          int row = hm * 32 + m * 16 + (lane >> 4) * 4 + r;
          #pragma unroll
          for (int n = 0; n < 2; ++n) {
            int col = colbase + n * 16 + (lane & 15);
            float v = fmaxf(h1[m][n][r] + eb1v[n], 0.f);
            int off = (row * 256 + col * 2) ^ ((row & 7) << 4);
            *(unsigned short*)((char*)shid + off) = f2bf_bits(v);
          }
        }
      }
    }
    __syncthreads();

    // ---- GEMM2 ----
    f32x4 acc[2][2];
    const f32x4 z = {0.f, 0.f, 0.f, 0.f};
    acc[0][0] = z; acc[0][1] = z; acc[1][0] = z; acc[1][1] = z;
    #pragma unroll
    for (int m = 0; m < 2; ++m) {
      #pragma unroll
      for (int kk = 0; kk < 4; ++kk) {
        int row = hm * 32 + m * 16 + (lane & 15);
        int off = (row * 256 + kk * 64 + (lane >> 4) * 16) ^ ((row & 7) << 4);
        short8v afrag = *(const short8v*)((const char*)shid + off);
        acc[m][0] = __builtin_amdgcn_mfma_f32_16x16x32_bf16(afrag, bfrag[0][kk], acc[m][0], 0, 0, 0);
        acc[m][1] = __builtin_amdgcn_mfma_f32_16x16x32_bf16(afrag, bfrag[1][kk], acc[m][1], 0, 0, 0);
      }
    }

    // ---- epilogue: run-length reduce into sagg (LDS), fallback atomics ----
    {
      float vs0 = 0.f, vs1 = 0.f, bv0 = 0.f, bv1 = 0.f;
      int liprev = -1, dprev = -1;
      #pragma unroll
      for (int m = 0; m < 2; ++m) {
        #pragma unroll
        for (int r = 0; r < 4; ++r) {
          int el = hm * 32 + m * 16 + (lane >> 4) * 4 + r;
          int j = base + el;
          bool own;
          int li;
          if (j < 64) {
            unsigned long long mk = b0 & ((2ull << j) - 1ull);
            own = mk != 0;
            li = (int)__popcll(mk) - 1;
          } else {
            own = ((b1 & ((2ull << (j - 64)) - 1ull)) == 0) && (b0 != 0);
            li = ndst - 1;
          }
          if (!own) li = -1;
          if (li != liprev) {
            if (liprev >= 0) {
              if (liprev < 16) {
                atomicAdd(&sagg[liprev * 128 + col0], vs0);
                atomicAdd(&sagg[liprev * 128 + col1], vs1);
              } else {
                atomicAdd(&agg[(size_t)dprev * H + col0], vs0);
                atomicAdd(&agg[(size_t)dprev * H + col1], vs1);
              }
            }
            vs0 = 0.f; vs1 = 0.f;
            liprev = li;
            if (li >= 0) {
              dprev = sdidx[1 + j];
              bv0 = __bfloat162float(B[(size_t)dprev * H + col0]);
              bv1 = __bfloat162float(B[(size_t)dprev * H + col1]);
            }
          }
          if (li >= 0) {
            float a0v = __bfloat162float(sAld[el][col0]);
            float a1v = __bfloat162float(sAld[el][col1]);
            vs0 += fmaxf(acc[m][0][r] + c3v[0] + a0v + bv0, 0.f);
            vs1 += fmaxf(acc[m][1][r] + c3v[1] + a1v + bv1, 0.f);
          }
        }
      }
      if (liprev >= 0) {
        if (liprev < 16) {
          atomicAdd(&sagg[liprev * 128 + col0], vs0);
          atomicAdd(&sagg[liprev * 128 + col1], vs1);
        } else {
          atomicAdd(&agg[(size_t)dprev * H + col0], vs0);
          atomicAdd(&agg[(size_t)dprev * H + col1], vs1);
        }
      }
    }
    __syncthreads();
  }

  // ---- flush owned runs: PLAIN STORES ----
  {
    int nli = ndst < 16 ? ndst : 16;
    for (int i = t; i < nli * 128; i += 512) {
      int li = i >> 7, col = i & 127;
      agg[(size_t)sgdst[li] * H + col] = sagg[i];
    }
  }
}

// ---------------------------------------------------------------------------
// Fused node update (MFMA):
//   h' = h + relu([h|agg] @ Wn + nb)          (K=256)
//   if DO_AB: A = bf16(h' @ W1next), B = bf16(h' @ W2next), agg = 0
// ---------------------------------------------------------------------------
template<int DO_AB>
__global__ __launch_bounds__(256) void fused_update_kernel(
    float* __restrict__ h, const float* __restrict__ aggin,
    const bf16* __restrict__ Wnb, const float* __restrict__ nb,
    const bf16* __restrict__ W1b, const bf16* __restrict__ W2b,
    bf16* __restrict__ A, bf16* __restrict__ B, float* __restrict__ aggz,
    int nrows)
{
  __shared__ unsigned int sKw[32 * 128];
  unsigned short* shnew = (unsigned short*)sKw;

  const int t = threadIdx.x;
  const int lane = t & 63;
  const int wid = t >> 6;
  const int colbase = wid * 32;

  short8v bU[2][8];
  float nbv[2];
  #pragma unroll
  for (int n = 0; n < 2; ++n) {
    int ng = wid * 2 + n;
    nbv[n] = nb[colbase + n * 16 + (lane & 15)];
    #pragma unroll
    for (int kk = 0; kk < 8; ++kk)
      bU[n][kk] = *(const short8v*)(Wnb + ((size_t)(ng * 8 + kk) * 64 + lane) * 8);
  }

  const int ntiles = (nrows + 31) / 32;
  for (int tile = blockIdx.x; tile < ntiles; tile += gridDim.x) {
    const int r0 = tile * 32;
    #pragma unroll
    for (int i = 0; i < 16; ++i) {
      int w = t + i * 256;
      int row = w >> 7, k2 = w & 127;
      int r = r0 + row;
      float v0 = 0.f, v1 = 0.f;
      if (r < nrows) {
        if (k2 < 64) { float2 p = *(const float2*)&h[(size_t)r * H + 2 * k2]; v0 = p.x; v1 = p.y; }
        else         { float2 p = *(const float2*)&aggin[(size_t)r * H + 2 * k2 - 128]; v0 = p.x; v1 = p.y; }
      }
      unsigned int wrd = (unsigned int)f2bf_bits(v0) | ((unsigned int)f2bf_bits(v1) << 16);
      sKw[((w * 4) ^ ((row & 7) << 4)) >> 2] = wrd;
    }
    __syncthreads();

    f32x4 acc[2][2];
    const f32x4 z = {0.f, 0.f, 0.f, 0.f};
    acc[0][0] = z; acc[0][1] = z; acc[1][0] = z; acc[1][1] = z;
    #pragma unroll
    for (int kk = 0; kk < 8; ++kk) {
      #pragma unroll
      for (int m = 0; m < 2; ++m) {
        int row = m * 16 + (lane & 15);
        int off = (row * 512 + kk * 64 + (lane >> 4) * 16) ^ ((row & 7) << 4);
        short8v afrag = *(const short8v*)((const char*)sKw + off);
        acc[m][0] = __builtin_amdgcn_mfma_f32_16x16x32_bf16(afrag, bU[0][kk], acc[m][0], 0, 0, 0);
        acc[m][1] = __builtin_amdgcn_mfma_f32_16x16x32_bf16(afrag, bU[1][kk], acc[m][1], 0, 0, 0);
      }
    }
    __syncthreads();

    #pragma unroll
    for (int m = 0; m < 2; ++m) {
      #pragma unroll
      for (int r = 0; r < 4; ++r) {
        int row = m * 16 + (lane >> 4) * 4 + r;
        int grow = r0 + row;
        #pragma unroll
        for (int n = 0; n < 2; ++n) {
          int col = colbase + n * 16 + (lane & 15);
          float u = fmaxf(acc[m][n][r] + nbv[n], 0.f);
          float hold = (grow < nrows) ? h[(size_t)grow * H + col] : 0.f;
          float hn = hold + u;
          if (grow < nrows) h[(size_t)grow * H + col] = hn;
          if (DO_AB) {
            int i16 = (row * 128 + col) ^ ((row & 7) << 3);
            shnew[i16] = f2bf_bits(hn);
          }
        }
      }
    }

    if (DO_AB) {
      __syncthreads();
      short8v bA[2][4], bB[2][4];
      #pragma unroll
      for (int n = 0; n < 2; ++n) {
        int ng = wid * 2 + n;
        #pragma unroll
        for (int kk = 0; kk < 4; ++kk) {
          bA[n][kk] = *(const short8v*)(W1b + ((size_t)(ng * 4 + kk) * 64 + lane) * 8);
          bB[n][kk] = *(const short8v*)(W2b + ((size_t)(ng * 4 + kk) * 64 + lane) * 8);
        }
      }
      f32x4 aA[2][2], aB2[2][2];
      aA[0][0] = z; aA[0][1] = z; aA[1][0] = z; aA[1][1] = z;
      aB2[0][0] = z; aB2[0][1] = z; aB2[1][0] = z; aB2[1][1] = z;
      #pragma unroll
      for (int kk = 0; kk < 4; ++kk) {
        #pragma unroll
        for (int m = 0; m < 2; ++m) {
          int row = m * 16 + (lane & 15);
          int off = (row * 256 + kk * 64 + (lane >> 4) * 16) ^ ((row & 7) << 4);
          short8v afrag = *(const short8v*)((const char*)shnew + off);
          aA[m][0] = __builtin_amdgcn_mfma_f32_16x16x32_bf16(afrag, bA[0][kk], aA[m][0], 0, 0, 0);
          aA[m][1] = __builtin_amdgcn_mfma_f32_16x16x32_bf16(afrag, bA[1][kk], aA[m][1], 0, 0, 0);
          aB2[m][0] = __builtin_amdgcn_mfma_f32_16x16x32_bf16(afrag, bB[0][kk], aB2[m][0], 0, 0, 0);
          aB2[m][1] = __builtin_amdgcn_mfma_f32_16x16x32_bf16(afrag, bB[1][kk], aB2[m][1], 0, 0, 0);
        }
      }
      #pragma unroll
      for (int m = 0; m < 2; ++m) {
        #pragma unroll
        for (int r = 0; r < 4; ++r) {
          int row = m * 16 + (lane >> 4) * 4 + r;
          int grow = r0 + row;
          if (grow < nrows) {
            #pragma unroll
            for (int n = 0; n < 2; ++n) {
              int col = colbase + n * 16 + (lane & 15);
              A[(size_t)grow * H + col] = __float2bfloat16(aA[m][n][r]);
              B[(size_t)grow * H + col] = __float2bfloat16(aB2[m][n][r]);
              aggz[(size_t)grow * H + col] = 0.f;
            }
          }
        }
      }
    }
    __syncthreads();
  }
}

// ---------------------------------------------------------------------------
// Decoder: pred = relu(relu(h@w1+b1)@w2+b2)@w3+b3, then BC mask.
// ---------------------------------------------------------------------------
__global__ __launch_bounds__(512) void decoder_kernel(
    const float* __restrict__ h,
    const float* __restrict__ w1, const float* __restrict__ b1,
    const float* __restrict__ w2, const float* __restrict__ b2,
    const float* __restrict__ w3, const float* __restrict__ b3,
    const float* __restrict__ bcd, const float* __restrict__ bcr,
    float* __restrict__ out, int nrows)
{
  __shared__ float sw1[H * H];
  __shared__ float sw2[H * 64];
  __shared__ float sw3[64 * 3];
  __shared__ float sb1[H], sb2[64], sb3[3];
  __shared__ float sh[16][H], st1[16][H], st2[16][64];
  for (int i = threadIdx.x; i < H * H; i += 512) sw1[i] = w1[i];
  for (int i = threadIdx.x; i < H * 64; i += 512) sw2[i] = w2[i];
  if (threadIdx.x < 64 * 3) sw3[threadIdx.x] = w3[threadIdx.x];
  if (threadIdx.x < H) sb1[threadIdx.x] = b1[threadIdx.x];
  if (threadIdx.x < 64) sb2[threadIdx.x] = b2[threadIdx.x];
  if (threadIdx.x < 3) sb3[threadIdx.x] = b3[threadIdx.x];
  __syncthreads();
  for (long long r0 = (long long)blockIdx.x * 16; r0 < nrows; r0 += (long long)gridDim.x * 16) {
    #pragma unroll
    for (int t = 0; t < 4; ++t) {
      int idx = threadIdx.x + t * 512;
      int j = idx >> 7, k = idx & 127;
      long long r = r0 + j;
      sh[j][k] = (r < nrows) ? h[r * H + k] : 0.f;
    }
    __syncthreads();
    #pragma unroll
    for (int t = 0; t < 4; ++t) {
      int idx = threadIdx.x + t * 512;
      int j = idx >> 7, k = idx & 127;
      float acc = sb1[k];
      #pragma unroll 8
      for (int i = 0; i < H; ++i) acc += sh[j][i] * sw1[i * H + k];
      st1[j][k] = fmaxf(acc, 0.f);
    }
    __syncthreads();
    #pragma unroll
    for (int t = 0; t < 2; ++t) {
      int idx = threadIdx.x + t * 512;
      int j = idx >> 6, k = idx & 63;
      float acc = sb2[k];
      #pragma unroll 8
      for (int i = 0; i < H; ++i) acc += st1[j][i] * sw2[i * 64 + k];
      st2[j][k] = fmaxf(acc, 0.f);
    }
    __syncthreads();
    if (threadIdx.x < 48) {
      int j = threadIdx.x / 3, o = threadIdx.x % 3;
      float acc = sb3[o];
      #pragma unroll 8
      for (int i = 0; i < 64; ++i) acc += st2[j][i] * sw3[i * 3 + o];
      long long r = r0 + j;
      if (r < nrows) {
        float m = (o < 2) ? (1.f - bcd[r]) : (1.f - bcr[r]);
        out[r * 3 + o] = acc * m;
      }
    }
    __syncthreads();
  }
}

extern "C" void kernel_launch(void* const* d_in, const int* in_sizes, int n_in,
                              void* d_out, int out_size, void* d_ws, size_t ws_size,
                              hipStream_t stream) {
  const float* x     = (const float*)d_in[0];
  const float* ea    = (const float*)d_in[1];
  const int*   eidx  = (const int*)d_in[2];
  const float* bcd   = (const float*)d_in[3];
  const float* bcr   = (const float*)d_in[4];
  const float* ne_w1 = (const float*)d_in[5];
  const float* ne_b1 = (const float*)d_in[6];
  const float* ne_w2 = (const float*)d_in[7];
  const float* ne_b2 = (const float*)d_in[8];
  const float* ee_w1 = (const float*)d_in[9];
  const float* ee_b1 = (const float*)d_in[10];
  const float* ee_w2 = (const float*)d_in[11];
  const float* ee_b2 = (const float*)d_in[12];
  const float* mp_ew = (const float*)d_in[13];
  const float* mp_eb = (const float*)d_in[14];
  const float* mp_nw = (const float*)d_in[15];
  const float* mp_nb = (const float*)d_in[16];
  const float* d_w1  = (const float*)d_in[17];
  const float* d_b1  = (const float*)d_in[18];
  const float* d_w2  = (const float*)d_in[19];
  const float* d_b2  = (const float*)d_in[20];
  const float* d_w3  = (const float*)d_in[21];
  const float* d_b3  = (const float*)d_in[22];

  const int* srcI = eidx;           // edge_index[0]
  const int* dstI = eidx + NE;      // edge_index[1]

  // workspace (~95.4 MB, fits 100 MiB)
  char* wsp = (char*)d_ws;
  float* h    = (float*)wsp; wsp += (size_t)NN * H * 4;          // 25.6 MB
  float* agg  = (float*)wsp; wsp += (size_t)NN * H * 4;          // 25.6 MB
  bf16*  A    = (bf16*)wsp;  wsp += (size_t)NN * H * 2;          // 12.8 MB
  bf16*  B    = (bf16*)wsp;  wsp += (size_t)NN * H * 2;          // 12.8 MB
  bf16*  eap  = (bf16*)wsp;  wsp += (size_t)NE * 7 * 2;          // 11.2 MB
  int*   srcp = (int*)wsp;   wsp += (size_t)NE * 4;              // 3.2 MB
  int*   dstp = (int*)wsp;   wsp += (size_t)NE * 4;              // 3.2 MB
  bf16*  W3b  = (bf16*)wsp;  wsp += (size_t)6 * H * H * 2;       // 0.20 MB
  bf16*  Wnb  = (bf16*)wsp;  wsp += (size_t)6 * 256 * H * 2;     // 0.39 MB
  bf16*  W1b  = (bf16*)wsp;  wsp += (size_t)6 * H * H * 2;       // 0.20 MB
  bf16*  W2b  = (bf16*)wsp;  wsp += (size_t)6 * H * H * 2;       // 0.20 MB
  float* c3   = (float*)wsp; wsp += (size_t)6 * H * 4;           // 3 KB
  int*   bsum = (int*)wsp;   wsp += 256 * 4;                     // scan partials
  // setup-time aliases (dead before their hosts are first written):
  int*   counts = (int*)A;
  int*   cursor = (int*)A + NN;
  float* W3p    = agg;

  // ---- dst-sort build (once; reused across all 6 layers) ----
  zero_counts_kernel<<<(NN + 255) / 256, 256, 0, stream>>>(counts);
  hist_kernel<<<(NE + 255) / 256, 256, 0, stream>>>(dstI, counts);
  scan1_kernel<<<NBLK, 256, 0, stream>>>(counts, bsum);
  scan2_kernel<<<1, 256, 0, stream>>>(bsum);
  scan3_kernel<<<NBLK, 256, 0, stream>>>(counts, bsum, cursor);
  scatter_kernel<<<(NE + 255) / 256, 256, 0, stream>>>(ea, srcI, dstI, cursor, eap, srcp, dstp);

  // ---- weight prep (one-time) ----
  fuse_w3_kernel<<<48, 256, 0, stream>>>(ee_w2, ee_b2, mp_ew, mp_eb, W3p, c3);
  repack_w_kernel<<<6, 256, 0, stream>>>(W3p, (size_t)H * H, W3b, 128);
  repack_w_kernel<<<6, 256, 0, stream>>>(mp_nw, (size_t)256 * H, Wnb, 256);
  repack_w_kernel<<<6, 256, 0, stream>>>(mp_ew, (size_t)384 * H, W1b, 128);
  repack_w_kernel<<<6, 256, 0, stream>>>(mp_ew + 128 * H, (size_t)384 * H, W2b, 128);

  node_encoder_kernel<<<2048, 256, 0, stream>>>(x, ne_w1, ne_b1, ne_w2, ne_b2, h, NN);
  node_AB_kernel<<<1024, 512, 0, stream>>>(h, mp_ew, mp_ew + 128 * H, A, B, agg, NN);

  for (int l = 0; l < 6; ++l) {
    edge_mfma_own<<<12500, 512, 0, stream>>>(eap, srcp, dstp, A, B, ee_w1, ee_b1,
                                             W3b + (size_t)l * H * H, c3 + l * H, agg, NE);
    if (l < 5) {
      fused_update_kernel<1><<<1563, 256, 0, stream>>>(
          h, agg, Wnb + (size_t)l * 256 * H, mp_nb + l * H,
          W1b + (size_t)(l + 1) * H * H, W2b + (size_t)(l + 1) * H * H,
          A, B, agg, NN);
    } else {
      fused_update_kernel<0><<<1563, 256, 0, stream>>>(
          h, agg, Wnb + (size_t)l * 256 * H, mp_nb + l * H,
          nullptr, nullptr, nullptr, nullptr, nullptr, NN);
    }
  }

  decoder_kernel<<<1024, 512, 0, stream>>>(h, d_w1, d_b1, d_w2, d_b2, d_w3, d_b3,
                                           bcd, bcr, (float*)d_out, NN);
}

// Round 15
// 2662.503 us; speedup vs baseline: 1.1411x; 1.1411x over previous
//
#include <hip/hip_runtime.h>
#include <hip/hip_bf16.h>

#define NN 50000
#define NE 800000
#define H 128
#define NBLK 196   // (NN+255)/256

typedef __hip_bfloat16 bf16;
typedef __attribute__((ext_vector_type(8))) short short8v;
typedef __attribute__((ext_vector_type(4))) float f32x4;

static __device__ __forceinline__ unsigned short f2bf_bits(float x) {
  union { __hip_bfloat16 b; unsigned short u; } cv;
  cv.b = __float2bfloat16(x);
  return cv.u;
}

// ---------------------------------------------------------------------------
// Sort-by-dst build: zero counts -> histogram -> hierarchical scan -> permute
// ---------------------------------------------------------------------------
__global__ __launch_bounds__(256) void zero_counts_kernel(int* __restrict__ counts) {
  int i = blockIdx.x * 256 + threadIdx.x;
  if (i < NN) counts[i] = 0;
}

__global__ __launch_bounds__(256) void hist_kernel(const int* __restrict__ dstI,
                                                   int* __restrict__ counts) {
  int e = blockIdx.x * 256 + threadIdx.x;
  if (e < NE) atomicAdd(&counts[dstI[e]], 1);
}

__global__ __launch_bounds__(256) void scan1_kernel(const int* __restrict__ counts,
                                                    int* __restrict__ bsum) {
  __shared__ int sdata[256];
  int i = blockIdx.x * 256 + threadIdx.x;
  sdata[threadIdx.x] = (i < NN) ? counts[i] : 0;
  __syncthreads();
  for (int off = 128; off > 0; off >>= 1) {
    if (threadIdx.x < off) sdata[threadIdx.x] += sdata[threadIdx.x + off];
    __syncthreads();
  }
  if (threadIdx.x == 0) bsum[blockIdx.x] = sdata[0];
}

__global__ __launch_bounds__(256) void scan2_kernel(int* __restrict__ bsum) {
  __shared__ int sdata[256];
  const int t = threadIdx.x;
  int v = (t < NBLK) ? bsum[t] : 0;
  sdata[t] = v;
  __syncthreads();
  #pragma unroll
  for (int off = 1; off < 256; off <<= 1) {
    int x = (t >= off) ? sdata[t - off] : 0;
    __syncthreads();
    sdata[t] += x;
    __syncthreads();
  }
  if (t < NBLK) bsum[t] = sdata[t] - v;   // exclusive
}

__global__ __launch_bounds__(256) void scan3_kernel(const int* __restrict__ counts,
                                                    const int* __restrict__ bsum,
                                                    int* __restrict__ cursor) {
  __shared__ int sdata[256];
  const int t = threadIdx.x;
  int i = blockIdx.x * 256 + t;
  int v = (i < NN) ? counts[i] : 0;
  sdata[t] = v;
  __syncthreads();
  #pragma unroll
  for (int off = 1; off < 256; off <<= 1) {
    int x = (t >= off) ? sdata[t - off] : 0;
    __syncthreads();
    sdata[t] += x;
    __syncthreads();
  }
  if (i < NN) cursor[i] = bsum[blockIdx.x] + sdata[t] - v;
}

__global__ __launch_bounds__(256) void scatter_kernel(
    const float* __restrict__ ea, const int* __restrict__ srcI, const int* __restrict__ dstI,
    int* __restrict__ cursor, bf16* __restrict__ eap,
    int* __restrict__ srcp, int* __restrict__ dstp) {
  int e = blockIdx.x * 256 + threadIdx.x;
  if (e >= NE) return;
  int d = dstI[e];
  int pos = atomicAdd(&cursor[d], 1);
  srcp[pos] = srcI[e];
  dstp[pos] = d;
  #pragma unroll
  for (int k = 0; k < 7; ++k) eap[(size_t)pos * 7 + k] = __float2bfloat16(ea[(size_t)e * 7 + k]);
}

// ---------------------------------------------------------------------------
// Fused edge weights: W3p[l] = ee_w2 @ W3[l], c3[l] = ee_b2 @ W3[l] + eb[l]
// ---------------------------------------------------------------------------
__global__ __launch_bounds__(256) void fuse_w3_kernel(
    const float* __restrict__ ee_w2, const float* __restrict__ ee_b2,
    const float* __restrict__ mp_ew, const float* __restrict__ mp_eb,
    float* __restrict__ W3p, float* __restrict__ c3)
{
  const int l = blockIdx.x >> 3;
  const int cc = (blockIdx.x & 7) * 16;
  __shared__ float sA[H * H];
  __shared__ float sB[H * 16];
  const float* W3 = mp_ew + (size_t)l * 384 * H + 256 * H;
  for (int i = threadIdx.x; i < H * H; i += 256) sA[i] = ee_w2[i];
  for (int i = threadIdx.x; i < H * 16; i += 256) {
    int k = i >> 4, j = i & 15;
    sB[i] = W3[k * H + cc + j];
  }
  __syncthreads();
  float* out = W3p + (size_t)l * H * H;
  for (int i = threadIdx.x; i < H * 16; i += 256) {
    int r = i >> 4, j = i & 15;
    float acc = 0.f;
    #pragma unroll 8
    for (int k = 0; k < H; ++k) acc += sA[r * H + k] * sB[k * 16 + j];
    out[r * H + cc + j] = acc;
  }
  if (threadIdx.x < 16) {
    int j = threadIdx.x;
    float acc = mp_eb[l * H + cc + j];
    for (int k = 0; k < H; ++k) acc += ee_b2[k] * sB[k * 16 + j];
    c3[l * H + cc + j] = acc;
  }
}

// ---------------------------------------------------------------------------
// Generic repack: [K x 128] f32 row-major -> bf16 MFMA B-fragment order.
// ---------------------------------------------------------------------------
__global__ __launch_bounds__(256) void repack_w_kernel(
    const float* __restrict__ src0, size_t lstride, bf16* __restrict__ dst0, int K)
{
  const int l = blockIdx.x;
  const float* src = src0 + (size_t)l * lstride;
  bf16* dst = dst0 + (size_t)l * K * 128;
  const int nkk = K / 32;
  const int nslots = 8 * nkk * 64;
  for (int idx = threadIdx.x; idx < nslots; idx += 256) {
    int ng = idx / (nkk * 64);
    int rem = idx % (nkk * 64);
    int kk = rem / 64, ln = rem % 64;
    #pragma unroll
    for (int j = 0; j < 8; ++j) {
      int k = kk * 32 + ((ln >> 4) * 8) + j;
      int col = ng * 16 + (ln & 15);
      dst[(size_t)idx * 8 + j] = __float2bfloat16(src[(size_t)k * 128 + col]);
    }
  }
}

// ---------------------------------------------------------------------------
// Node encoder: h = relu(x @ w1 + b1) @ w2 + b2   (10 -> 128 -> 128)
// ---------------------------------------------------------------------------
__global__ __launch_bounds__(256) void node_encoder_kernel(
    const float* __restrict__ in,
    const float* __restrict__ w1, const float* __restrict__ b1,
    const float* __restrict__ w2, const float* __restrict__ b2,
    float* __restrict__ out, int nrows)
{
  __shared__ float sw1[10 * H];
  __shared__ float sw2[H * H];
  __shared__ float sb1[H];
  __shared__ float sb2[H];
  __shared__ float sin_[8][10];
  __shared__ float st[8][H];

  for (int i = threadIdx.x; i < 10 * H; i += 256) sw1[i] = w1[i];
  for (int i = threadIdx.x; i < H * H; i += 256) sw2[i] = w2[i];
  if (threadIdx.x < H) { sb1[threadIdx.x] = b1[threadIdx.x]; sb2[threadIdx.x] = b2[threadIdx.x]; }
  __syncthreads();

  const int c = threadIdx.x & 127;
  const int hf = threadIdx.x >> 7;

  for (long long r0 = (long long)blockIdx.x * 8; r0 < nrows; r0 += (long long)gridDim.x * 8) {
    if (threadIdx.x < 80) {
      int j = threadIdx.x / 10, k = threadIdx.x % 10;
      long long r = r0 + j;
      sin_[j][k] = (r < nrows) ? in[r * 10 + k] : 0.f;
    }
    __syncthreads();
    #pragma unroll
    for (int t = 0; t < 4; ++t) {
      int idx = threadIdx.x + t * 256;
      int j = idx >> 7, k = idx & 127;
      float acc = sb1[k];
      #pragma unroll
      for (int i = 0; i < 10; ++i) acc += sin_[j][i] * sw1[i * H + k];
      st[j][k] = fmaxf(acc, 0.f);
    }
    __syncthreads();
    float a0 = sb2[c], a1 = a0, a2 = a0, a3 = a0;
    #pragma unroll 4
    for (int k4 = 0; k4 < H; k4 += 4) {
      float w0 = sw2[(k4 + 0) * H + c];
      float w1v = sw2[(k4 + 1) * H + c];
      float w2v = sw2[(k4 + 2) * H + c];
      float w3v = sw2[(k4 + 3) * H + c];
      float4 s0 = *(const float4*)&st[hf * 4 + 0][k4];
      float4 s1 = *(const float4*)&st[hf * 4 + 1][k4];
      float4 s2 = *(const float4*)&st[hf * 4 + 2][k4];
      float4 s3 = *(const float4*)&st[hf * 4 + 3][k4];
      a0 += s0.x * w0 + s0.y * w1v + s0.z * w2v + s0.w * w3v;
      a1 += s1.x * w0 + s1.y * w1v + s1.z * w2v + s1.w * w3v;
      a2 += s2.x * w0 + s2.y * w1v + s2.z * w2v + s2.w * w3v;
      a3 += s3.x * w0 + s3.y * w1v + s3.z * w2v + s3.w * w3v;
    }
    float accs[4] = {a0, a1, a2, a3};
    #pragma unroll
    for (int j = 0; j < 4; ++j) {
      long long r = r0 + hf * 4 + j;
      if (r < nrows) out[r * H + c] = accs[j];
    }
    __syncthreads();
  }
}

// ---------------------------------------------------------------------------
// Layer-0 node GEMMs (fp32): A = bf16(h @ W1), B = bf16(h @ W2); zeroes agg.
// ---------------------------------------------------------------------------
__global__ __launch_bounds__(512) void node_AB_kernel(
    const float* __restrict__ h, const float* __restrict__ W1f, const float* __restrict__ W2f,
    bf16* __restrict__ A, bf16* __restrict__ B, float* __restrict__ agg, int nrows)
{
  __shared__ float sw1[H * H];
  __shared__ float sw2[H * H];
  __shared__ float sh[16][H];
  for (int i = threadIdx.x; i < H * H; i += 512) { sw1[i] = W1f[i]; sw2[i] = W2f[i]; }
  __syncthreads();
  const int c = threadIdx.x & 127;
  const int q = threadIdx.x >> 7;
  for (long long r0 = (long long)blockIdx.x * 16; r0 < nrows; r0 += (long long)gridDim.x * 16) {
    #pragma unroll
    for (int t = 0; t < 4; ++t) {
      int idx = threadIdx.x + t * 512;
      int j = idx >> 7, k = idx & 127;
      long long r = r0 + j;
      sh[j][k] = (r < nrows) ? h[r * H + k] : 0.f;
    }
    __syncthreads();
    float aA[4] = {0, 0, 0, 0}, aB[4] = {0, 0, 0, 0};
    #pragma unroll 2
    for (int k4 = 0; k4 < H; k4 += 4) {
      float w10 = sw1[(k4 + 0) * H + c], w11 = sw1[(k4 + 1) * H + c];
      float w12 = sw1[(k4 + 2) * H + c], w13 = sw1[(k4 + 3) * H + c];
      float w20 = sw2[(k4 + 0) * H + c], w21 = sw2[(k4 + 1) * H + c];
      float w22 = sw2[(k4 + 2) * H + c], w23 = sw2[(k4 + 3) * H + c];
      #pragma unroll
      for (int j = 0; j < 4; ++j) {
        float4 s = *(const float4*)&sh[q * 4 + j][k4];
        aA[j] += s.x * w10 + s.y * w11 + s.z * w12 + s.w * w13;
        aB[j] += s.x * w20 + s.y * w21 + s.z * w22 + s.w * w23;
      }
    }
    #pragma unroll
    for (int j = 0; j < 4; ++j) {
      long long r = r0 + q * 4 + j;
      if (r < nrows) {
        A[r * H + c] = __float2bfloat16(aA[j]);
        B[r * H + c] = __float2bfloat16(aB[j]);
        agg[r * H + c] = 0.f;
      }
    }
    __syncthreads();
  }
}

// ---------------------------------------------------------------------------
// Edge kernel (r12 best: MFMA GEMM2, dst-sorted, LDS A-staging, run-length
// atomics, one-tile-ahead register prefetch, exact 2 tiles/block).
// ---------------------------------------------------------------------------
__global__ __launch_bounds__(512) void edge_mfma_scatter(
    const bf16* __restrict__ eap,
    const int* __restrict__ srcp, const int* __restrict__ dstp,
    const bf16* __restrict__ A, const bf16* __restrict__ B,
    const float* __restrict__ ew1, const float* __restrict__ eb1,
    const bf16* __restrict__ W3b, const float* __restrict__ c3,
    float* __restrict__ agg, int nE)
{
  __shared__ float sew1[7 * H];           // 3.5 KB
  __shared__ float seb1[H];               // 0.5 KB
  __shared__ float sea[64][8];            // 2 KB
  __shared__ int   didx[64];
  __shared__ unsigned int shid[64 * 64];  // 16 KB, bf16x2 swizzled
  __shared__ bf16  sAld[64][136];         // 17 KB staged A rows (+8 pad)

  for (int i = threadIdx.x; i < 7 * H; i += 512) sew1[i] = ew1[i];
  if (threadIdx.x < H) seb1[threadIdx.x] = eb1[threadIdx.x];

  const int t = threadIdx.x;
  const int lane = t & 63;
  const int wid = t >> 6;                 // 0..7
  const int hm = wid >> 2;                // row half
  const int colbase = (wid & 3) * 32;     // col slice

  short8v bfrag[2][4];
  float c3v[2];
  #pragma unroll
  for (int n = 0; n < 2; ++n) {
    c3v[n] = c3[colbase + n * 16 + (lane & 15)];
    int ng = (colbase >> 4) + n;
    #pragma unroll
    for (int kk = 0; kk < 4; ++kk) {
      const bf16* p = W3b + ((size_t)(ng * 4 + kk) * 64 + lane) * 8;
      bfrag[n][kk] = *(const short8v*)p;
    }
  }
  __syncthreads();

  const long long stride = (long long)gridDim.x * 64;
  const int elA0 = t >> 4;
  const int elA1 = 32 + (t >> 4);
  const int segA = (t & 15) * 8;

  // ---- prologue prefetch ----
  float   pf_ea = 0.f;
  int     pf_d = 0;
  short8v pf_A0, pf_A1;
  long long e0 = (long long)blockIdx.x * 64;
  if (e0 < nE) {
    if (t < 448) pf_ea = __bfloat162float(eap[e0 * 7 + t]);
    if (t < 64)  pf_d = dstp[e0 + t];
    int s0 = srcp[e0 + elA0];
    pf_A0 = *(const short8v*)&A[(size_t)s0 * H + segA];
    int s1 = srcp[e0 + elA1];
    pf_A1 = *(const short8v*)&A[(size_t)s1 * H + segA];
  }

  for (; e0 < nE; e0 += stride) {
    if (t < 448) sea[t / 7][t % 7] = pf_ea;
    if (t < 64)  didx[t] = pf_d;
    *(short8v*)&sAld[elA0][segA] = pf_A0;
    *(short8v*)&sAld[elA1][segA] = pf_A1;
    __syncthreads();

    long long e1 = e0 + stride;
    if (e1 < nE) {
      if (t < 448) pf_ea = __bfloat162float(eap[e1 * 7 + t]);
      if (t < 64)  pf_d = dstp[e1 + t];
      int s0 = srcp[e1 + elA0];
      pf_A0 = *(const short8v*)&A[(size_t)s0 * H + segA];
      int s1 = srcp[e1 + elA1];
      pf_A1 = *(const short8v*)&A[(size_t)s1 * H + segA];
    }

    // ---- hidden layer ----
    {
      const int e = t >> 3;
      float r0 = sea[e][0], r1 = sea[e][1], r2 = sea[e][2], r3 = sea[e][3];
      float r4 = sea[e][4], r5 = sea[e][5], r6 = sea[e][6];
      #pragma unroll
      for (int p = 0; p < 8; ++p) {
        int k2 = (t & 7) + 8 * p;
        int k = k2 * 2;
        float a0 = seb1[k], a1 = seb1[k + 1];
        a0 += r0 * sew1[0 * H + k] + r1 * sew1[1 * H + k] + r2 * sew1[2 * H + k]
            + r3 * sew1[3 * H + k] + r4 * sew1[4 * H + k] + r5 * sew1[5 * H + k]
            + r6 * sew1[6 * H + k];
        a1 += r0 * sew1[0 * H + k + 1] + r1 * sew1[1 * H + k + 1] + r2 * sew1[2 * H + k + 1]
            + r3 * sew1[3 * H + k + 1] + r4 * sew1[4 * H + k + 1] + r5 * sew1[5 * H + k + 1]
            + r6 * sew1[6 * H + k + 1];
        a0 = fmaxf(a0, 0.f); a1 = fmaxf(a1, 0.f);
        unsigned int w = (unsigned int)f2bf_bits(a0) | ((unsigned int)f2bf_bits(a1) << 16);
        int off = (e * 256 + k2 * 4) ^ ((e & 7) << 4);
        shid[off >> 2] = w;
      }
    }
    __syncthreads();

    // ---- GEMM2 ----
    f32x4 acc[2][2];
    const f32x4 z = {0.f, 0.f, 0.f, 0.f};
    acc[0][0] = z; acc[0][1] = z; acc[1][0] = z; acc[1][1] = z;
    #pragma unroll
    for (int m = 0; m < 2; ++m) {
      #pragma unroll
      for (int kk = 0; kk < 4; ++kk) {
        int row = hm * 32 + m * 16 + (lane & 15);
        int off = (row * 256 + kk * 64 + (lane >> 4) * 16) ^ ((row & 7) << 4);
        short8v afrag = *(const short8v*)((const char*)shid + off);
        acc[m][0] = __builtin_amdgcn_mfma_f32_16x16x32_bf16(afrag, bfrag[0][kk], acc[m][0], 0, 0, 0);
        acc[m][1] = __builtin_amdgcn_mfma_f32_16x16x32_bf16(afrag, bfrag[1][kk], acc[m][1], 0, 0, 0);
      }
    }

    // ---- epilogue: run-length reduce equal-dst rows, atomic ----
    const int col0 = colbase + (lane & 15);
    const int col1 = col0 + 16;
    #pragma unroll
    for (int m = 0; m < 2; ++m) {
      float vs0 = 0.f, vs1 = 0.f;
      float b0 = 0.f, b1 = 0.f;
      int dprev = -1;
      #pragma unroll
      for (int r = 0; r < 4; ++r) {
        int el = hm * 32 + m * 16 + (lane >> 4) * 4 + r;
        int d = didx[el];
        if (d != dprev) {
          if (dprev >= 0) {
            atomicAdd(&agg[(size_t)dprev * H + col0], vs0);
            atomicAdd(&agg[(size_t)dprev * H + col1], vs1);
          }
          vs0 = 0.f; vs1 = 0.f;
          b0 = __bfloat162float(B[(size_t)d * H + col0]);
          b1 = __bfloat162float(B[(size_t)d * H + col1]);
          dprev = d;
        }
        float a0v = __bfloat162float(sAld[el][col0]);
        float a1v = __bfloat162float(sAld[el][col1]);
        vs0 += fmaxf(acc[m][0][r] + c3v[0] + a0v + b0, 0.f);
        vs1 += fmaxf(acc[m][1][r] + c3v[1] + a1v + b1, 0.f);
      }
      atomicAdd(&agg[(size_t)dprev * H + col0], vs0);
      atomicAdd(&agg[(size_t)dprev * H + col1], vs1);
    }
    __syncthreads();
  }
}

// ---------------------------------------------------------------------------
// Fused node update (MFMA):
//   h' = h + relu([h|agg] @ Wn + nb)          (K=256)
//   if DO_AB: A = bf16(h' @ W1next), B = bf16(h' @ W2next), agg = 0
// Grid 521 = exactly 3 tiles/block: weight-fragment loads (128KB/block)
// amortized over 3 tiles instead of 1.
// ---------------------------------------------------------------------------
template<int DO_AB>
__global__ __launch_bounds__(256) void fused_update_kernel(
    float* __restrict__ h, const float* __restrict__ aggin,
    const bf16* __restrict__ Wnb, const float* __restrict__ nb,
    const bf16* __restrict__ W1b, const bf16* __restrict__ W2b,
    bf16* __restrict__ A, bf16* __restrict__ B, float* __restrict__ aggz,
    int nrows)
{
  __shared__ unsigned int sKw[32 * 128];
  unsigned short* shnew = (unsigned short*)sKw;

  const int t = threadIdx.x;
  const int lane = t & 63;
  const int wid = t >> 6;
  const int colbase = wid * 32;

  short8v bU[2][8];
  float nbv[2];
  #pragma unroll
  for (int n = 0; n < 2; ++n) {
    int ng = wid * 2 + n;
    nbv[n] = nb[colbase + n * 16 + (lane & 15)];
    #pragma unroll
    for (int kk = 0; kk < 8; ++kk)
      bU[n][kk] = *(const short8v*)(Wnb + ((size_t)(ng * 8 + kk) * 64 + lane) * 8);
  }
  short8v bA[2][4], bB[2][4];
  if (DO_AB) {
    #pragma unroll
    for (int n = 0; n < 2; ++n) {
      int ng = wid * 2 + n;
      #pragma unroll
      for (int kk = 0; kk < 4; ++kk) {
        bA[n][kk] = *(const short8v*)(W1b + ((size_t)(ng * 4 + kk) * 64 + lane) * 8);
        bB[n][kk] = *(const short8v*)(W2b + ((size_t)(ng * 4 + kk) * 64 + lane) * 8);
      }
    }
  }

  const int ntiles = (nrows + 31) / 32;
  for (int tile = blockIdx.x; tile < ntiles; tile += gridDim.x) {
    const int r0 = tile * 32;
    #pragma unroll
    for (int i = 0; i < 16; ++i) {
      int w = t + i * 256;
      int row = w >> 7, k2 = w & 127;
      int r = r0 + row;
      float v0 = 0.f, v1 = 0.f;
      if (r < nrows) {
        if (k2 < 64) { float2 p = *(const float2*)&h[(size_t)r * H + 2 * k2]; v0 = p.x; v1 = p.y; }
        else         { float2 p = *(const float2*)&aggin[(size_t)r * H + 2 * k2 - 128]; v0 = p.x; v1 = p.y; }
      }
      unsigned int wrd = (unsigned int)f2bf_bits(v0) | ((unsigned int)f2bf_bits(v1) << 16);
      sKw[((w * 4) ^ ((row & 7) << 4)) >> 2] = wrd;
    }
    __syncthreads();

    f32x4 acc[2][2];
    const f32x4 z = {0.f, 0.f, 0.f, 0.f};
    acc[0][0] = z; acc[0][1] = z; acc[1][0] = z; acc[1][1] = z;
    #pragma unroll
    for (int kk = 0; kk < 8; ++kk) {
      #pragma unroll
      for (int m = 0; m < 2; ++m) {
        int row = m * 16 + (lane & 15);
        int off = (row * 512 + kk * 64 + (lane >> 4) * 16) ^ ((row & 7) << 4);
        short8v afrag = *(const short8v*)((const char*)sKw + off);
        acc[m][0] = __builtin_amdgcn_mfma_f32_16x16x32_bf16(afrag, bU[0][kk], acc[m][0], 0, 0, 0);
        acc[m][1] = __builtin_amdgcn_mfma_f32_16x16x32_bf16(afrag, bU[1][kk], acc[m][1], 0, 0, 0);
      }
    }
    __syncthreads();

    #pragma unroll
    for (int m = 0; m < 2; ++m) {
      #pragma unroll
      for (int r = 0; r < 4; ++r) {
        int row = m * 16 + (lane >> 4) * 4 + r;
        int grow = r0 + row;
        #pragma unroll
        for (int n = 0; n < 2; ++n) {
          int col = colbase + n * 16 + (lane & 15);
          float u = fmaxf(acc[m][n][r] + nbv[n], 0.f);
          float hold = (grow < nrows) ? h[(size_t)grow * H + col] : 0.f;
          float hn = hold + u;
          if (grow < nrows) h[(size_t)grow * H + col] = hn;
          if (DO_AB) {
            int i16 = (row * 128 + col) ^ ((row & 7) << 3);
            shnew[i16] = f2bf_bits(hn);
          }
        }
      }
    }

    if (DO_AB) {
      __syncthreads();
      f32x4 aA[2][2], aB2[2][2];
      aA[0][0] = z; aA[0][1] = z; aA[1][0] = z; aA[1][1] = z;
      aB2[0][0] = z; aB2[0][1] = z; aB2[1][0] = z; aB2[1][1] = z;
      #pragma unroll
      for (int kk = 0; kk < 4; ++kk) {
        #pragma unroll
        for (int m = 0; m < 2; ++m) {
          int row = m * 16 + (lane & 15);
          int off = (row * 256 + kk * 64 + (lane >> 4) * 16) ^ ((row & 7) << 4);
          short8v afrag = *(const short8v*)((const char*)shnew + off);
          aA[m][0] = __builtin_amdgcn_mfma_f32_16x16x32_bf16(afrag, bA[0][kk], aA[m][0], 0, 0, 0);
          aA[m][1] = __builtin_amdgcn_mfma_f32_16x16x32_bf16(afrag, bA[1][kk], aA[m][1], 0, 0, 0);
          aB2[m][0] = __builtin_amdgcn_mfma_f32_16x16x32_bf16(afrag, bB[0][kk], aB2[m][0], 0, 0, 0);
          aB2[m][1] = __builtin_amdgcn_mfma_f32_16x16x32_bf16(afrag, bB[1][kk], aB2[m][1], 0, 0, 0);
        }
      }
      #pragma unroll
      for (int m = 0; m < 2; ++m) {
        #pragma unroll
        for (int r = 0; r < 4; ++r) {
          int row = m * 16 + (lane >> 4) * 4 + r;
          int grow = r0 + row;
          if (grow < nrows) {
            #pragma unroll
            for (int n = 0; n < 2; ++n) {
              int col = colbase + n * 16 + (lane & 15);
              A[(size_t)grow * H + col] = __float2bfloat16(aA[m][n][r]);
              B[(size_t)grow * H + col] = __float2bfloat16(aB2[m][n][r]);
              aggz[(size_t)grow * H + col] = 0.f;
            }
          }
        }
      }
    }
    __syncthreads();
  }
}

// ---------------------------------------------------------------------------
// Decoder: pred = relu(relu(h@w1+b1)@w2+b2)@w3+b3, then BC mask.
// ---------------------------------------------------------------------------
__global__ __launch_bounds__(512) void decoder_kernel(
    const float* __restrict__ h,
    const float* __restrict__ w1, const float* __restrict__ b1,
    const float* __restrict__ w2, const float* __restrict__ b2,
    const float* __restrict__ w3, const float* __restrict__ b3,
    const float* __restrict__ bcd, const float* __restrict__ bcr,
    float* __restrict__ out, int nrows)
{
  __shared__ float sw1[H * H];
  __shared__ float sw2[H * 64];
  __shared__ float sw3[64 * 3];
  __shared__ float sb1[H], sb2[64], sb3[3];
  __shared__ float sh[16][H], st1[16][H], st2[16][64];
  for (int i = threadIdx.x; i < H * H; i += 512) sw1[i] = w1[i];
  for (int i = threadIdx.x; i < H * 64; i += 512) sw2[i] = w2[i];
  if (threadIdx.x < 64 * 3) sw3[threadIdx.x] = w3[threadIdx.x];
  if (threadIdx.x < H) sb1[threadIdx.x] = b1[threadIdx.x];
  if (threadIdx.x < 64) sb2[threadIdx.x] = b2[threadIdx.x];
  if (threadIdx.x < 3) sb3[threadIdx.x] = b3[threadIdx.x];
  __syncthreads();
  for (long long r0 = (long long)blockIdx.x * 16; r0 < nrows; r0 += (long long)gridDim.x * 16) {
    #pragma unroll
    for (int t = 0; t < 4; ++t) {
      int idx = threadIdx.x + t * 512;
      int j = idx >> 7, k = idx & 127;
      long long r = r0 + j;
      sh[j][k] = (r < nrows) ? h[r * H + k] : 0.f;
    }
    __syncthreads();
    #pragma unroll
    for (int t = 0; t < 4; ++t) {
      int idx = threadIdx.x + t * 512;
      int j = idx >> 7, k = idx & 127;
      float acc = sb1[k];
      #pragma unroll 8
      for (int i = 0; i < H; ++i) acc += sh[j][i] * sw1[i * H + k];
      st1[j][k] = fmaxf(acc, 0.f);
    }
    __syncthreads();
    #pragma unroll
    for (int t = 0; t < 2; ++t) {
      int idx = threadIdx.x + t * 512;
      int j = idx >> 6, k = idx & 63;
      float acc = sb2[k];
      #pragma unroll 8
      for (int i = 0; i < H; ++i) acc += st1[j][i] * sw2[i * 64 + k];
      st2[j][k] = fmaxf(acc, 0.f);
    }
    __syncthreads();
    if (threadIdx.x < 48) {
      int j = threadIdx.x / 3, o = threadIdx.x % 3;
      float acc = sb3[o];
      #pragma unroll 8
      for (int i = 0; i < 64; ++i) acc += st2[j][i] * sw3[i * 3 + o];
      long long r = r0 + j;
      if (r < nrows) {
        float m = (o < 2) ? (1.f - bcd[r]) : (1.f - bcr[r]);
        out[r * 3 + o] = acc * m;
      }
    }
    __syncthreads();
  }
}

extern "C" void kernel_launch(void* const* d_in, const int* in_sizes, int n_in,
                              void* d_out, int out_size, void* d_ws, size_t ws_size,
                              hipStream_t stream) {
  const float* x     = (const float*)d_in[0];
  const float* ea    = (const float*)d_in[1];
  const int*   eidx  = (const int*)d_in[2];
  const float* bcd   = (const float*)d_in[3];
  const float* bcr   = (const float*)d_in[4];
  const float* ne_w1 = (const float*)d_in[5];
  const float* ne_b1 = (const float*)d_in[6];
  const float* ne_w2 = (const float*)d_in[7];
  const float* ne_b2 = (const float*)d_in[8];
  const float* ee_w1 = (const float*)d_in[9];
  const float* ee_b1 = (const float*)d_in[10];
  const float* ee_w2 = (const float*)d_in[11];
  const float* ee_b2 = (const float*)d_in[12];
  const float* mp_ew = (const float*)d_in[13];
  const float* mp_eb = (const float*)d_in[14];
  const float* mp_nw = (const float*)d_in[15];
  const float* mp_nb = (const float*)d_in[16];
  const float* d_w1  = (const float*)d_in[17];
  const float* d_b1  = (const float*)d_in[18];
  const float* d_w2  = (const float*)d_in[19];
  const float* d_b2  = (const float*)d_in[20];
  const float* d_w3  = (const float*)d_in[21];
  const float* d_b3  = (const float*)d_in[22];

  const int* srcI = eidx;           // edge_index[0]
  const int* dstI = eidx + NE;      // edge_index[1]

  // workspace (~95.4 MB, fits 100 MiB)
  char* wsp = (char*)d_ws;
  float* h    = (float*)wsp; wsp += (size_t)NN * H * 4;          // 25.6 MB
  float* agg  = (float*)wsp; wsp += (size_t)NN * H * 4;          // 25.6 MB
  bf16*  A    = (bf16*)wsp;  wsp += (size_t)NN * H * 2;          // 12.8 MB
  bf16*  B    = (bf16*)wsp;  wsp += (size_t)NN * H * 2;          // 12.8 MB
  bf16*  eap  = (bf16*)wsp;  wsp += (size_t)NE * 7 * 2;          // 11.2 MB
  int*   srcp = (int*)wsp;   wsp += (size_t)NE * 4;              // 3.2 MB
  int*   dstp = (int*)wsp;   wsp += (size_t)NE * 4;              // 3.2 MB
  bf16*  W3b  = (bf16*)wsp;  wsp += (size_t)6 * H * H * 2;       // 0.20 MB
  bf16*  Wnb  = (bf16*)wsp;  wsp += (size_t)6 * 256 * H * 2;     // 0.39 MB
  bf16*  W1b  = (bf16*)wsp;  wsp += (size_t)6 * H * H * 2;       // 0.20 MB
  bf16*  W2b  = (bf16*)wsp;  wsp += (size_t)6 * H * H * 2;       // 0.20 MB
  float* c3   = (float*)wsp; wsp += (size_t)6 * H * 4;           // 3 KB
  int*   bsum = (int*)wsp;   wsp += 256 * 4;                     // scan partials
  // setup-time aliases (dead before their hosts are first written):
  int*   counts = (int*)A;
  int*   cursor = (int*)A + NN;
  float* W3p    = agg;

  // ---- dst-sort build (once; reused across all 6 layers) ----
  zero_counts_kernel<<<(NN + 255) / 256, 256, 0, stream>>>(counts);
  hist_kernel<<<(NE + 255) / 256, 256, 0, stream>>>(dstI, counts);
  scan1_kernel<<<NBLK, 256, 0, stream>>>(counts, bsum);
  scan2_kernel<<<1, 256, 0, stream>>>(bsum);
  scan3_kernel<<<NBLK, 256, 0, stream>>>(counts, bsum, cursor);
  scatter_kernel<<<(NE + 255) / 256, 256, 0, stream>>>(ea, srcI, dstI, cursor, eap, srcp, dstp);

  // ---- weight prep (one-time) ----
  fuse_w3_kernel<<<48, 256, 0, stream>>>(ee_w2, ee_b2, mp_ew, mp_eb, W3p, c3);
  repack_w_kernel<<<6, 256, 0, stream>>>(W3p, (size_t)H * H, W3b, 128);
  repack_w_kernel<<<6, 256, 0, stream>>>(mp_nw, (size_t)256 * H, Wnb, 256);
  repack_w_kernel<<<6, 256, 0, stream>>>(mp_ew, (size_t)384 * H, W1b, 128);
  repack_w_kernel<<<6, 256, 0, stream>>>(mp_ew + 128 * H, (size_t)384 * H, W2b, 128);

  node_encoder_kernel<<<2048, 256, 0, stream>>>(x, ne_w1, ne_b1, ne_w2, ne_b2, h, NN);
  node_AB_kernel<<<1024, 512, 0, stream>>>(h, mp_ew, mp_ew + 128 * H, A, B, agg, NN);

  for (int l = 0; l < 6; ++l) {
    // grid 6250: 800000/64 = 12500 tiles -> exactly 2 tiles/block
    edge_mfma_scatter<<<6250, 512, 0, stream>>>(eap, srcp, dstp, A, B, ee_w1, ee_b1,
                                                W3b + (size_t)l * H * H, c3 + l * H, agg, NE);
    if (l < 5) {
      // grid 521: 1563 tiles -> exactly 3 tiles/block (weight amortization)
      fused_update_kernel<1><<<521, 256, 0, stream>>>(
          h, agg, Wnb + (size_t)l * 256 * H, mp_nb + l * H,
          W1b + (size_t)(l + 1) * H * H, W2b + (size_t)(l + 1) * H * H,
          A, B, agg, NN);
    } else {
      fused_update_kernel<0><<<521, 256, 0, stream>>>(
          h, agg, Wnb + (size_t)l * 256 * H, mp_nb + l * H,
          nullptr, nullptr, nullptr, nullptr, nullptr, NN);
    }
  }

  decoder_kernel<<<1024, 512, 0, stream>>>(h, d_w1, d_b1, d_w2, d_b2, d_w3, d_b3,
                                           bcd, bcr, (float*)d_out, NN);
}

// Round 16
// 2650.403 us; speedup vs baseline: 1.1463x; 1.0046x over previous
//
#include <hip/hip_runtime.h>
#include <hip/hip_bf16.h>

#define NN 50000
#define NE 800000
#define H 128
#define NBLK 196   // (NN+255)/256

typedef __hip_bfloat16 bf16;
typedef __attribute__((ext_vector_type(8))) short short8v;
typedef __attribute__((ext_vector_type(4))) float f32x4;

static __device__ __forceinline__ unsigned short f2bf_bits(float x) {
  union { __hip_bfloat16 b; unsigned short u; } cv;
  cv.b = __float2bfloat16(x);
  return cv.u;
}

// LDS-only barrier: waits DS ops, lets global loads/atomics stay in flight
// (__syncthreads would drain vmcnt(0), exposing prefetch + atomic latency).
static __device__ __forceinline__ void lds_barrier() {
  asm volatile("s_waitcnt lgkmcnt(0)" ::: "memory");
  __builtin_amdgcn_s_barrier();
}

// ---------------------------------------------------------------------------
// Sort-by-dst build: zero counts -> histogram -> hierarchical scan -> permute
// ---------------------------------------------------------------------------
__global__ __launch_bounds__(256) void zero_counts_kernel(int* __restrict__ counts) {
  int i = blockIdx.x * 256 + threadIdx.x;
  if (i < NN) counts[i] = 0;
}

__global__ __launch_bounds__(256) void hist_kernel(const int* __restrict__ dstI,
                                                   int* __restrict__ counts) {
  int e = blockIdx.x * 256 + threadIdx.x;
  if (e < NE) atomicAdd(&counts[dstI[e]], 1);
}

__global__ __launch_bounds__(256) void scan1_kernel(const int* __restrict__ counts,
                                                    int* __restrict__ bsum) {
  __shared__ int sdata[256];
  int i = blockIdx.x * 256 + threadIdx.x;
  sdata[threadIdx.x] = (i < NN) ? counts[i] : 0;
  __syncthreads();
  for (int off = 128; off > 0; off >>= 1) {
    if (threadIdx.x < off) sdata[threadIdx.x] += sdata[threadIdx.x + off];
    __syncthreads();
  }
  if (threadIdx.x == 0) bsum[blockIdx.x] = sdata[0];
}

__global__ __launch_bounds__(256) void scan2_kernel(int* __restrict__ bsum) {
  __shared__ int sdata[256];
  const int t = threadIdx.x;
  int v = (t < NBLK) ? bsum[t] : 0;
  sdata[t] = v;
  __syncthreads();
  #pragma unroll
  for (int off = 1; off < 256; off <<= 1) {
    int x = (t >= off) ? sdata[t - off] : 0;
    __syncthreads();
    sdata[t] += x;
    __syncthreads();
  }
  if (t < NBLK) bsum[t] = sdata[t] - v;   // exclusive
}

__global__ __launch_bounds__(256) void scan3_kernel(const int* __restrict__ counts,
                                                    const int* __restrict__ bsum,
                                                    int* __restrict__ cursor) {
  __shared__ int sdata[256];
  const int t = threadIdx.x;
  int i = blockIdx.x * 256 + t;
  int v = (i < NN) ? counts[i] : 0;
  sdata[t] = v;
  __syncthreads();
  #pragma unroll
  for (int off = 1; off < 256; off <<= 1) {
    int x = (t >= off) ? sdata[t - off] : 0;
    __syncthreads();
    sdata[t] += x;
    __syncthreads();
  }
  if (i < NN) cursor[i] = bsum[blockIdx.x] + sdata[t] - v;
}

__global__ __launch_bounds__(256) void scatter_kernel(
    const float* __restrict__ ea, const int* __restrict__ srcI, const int* __restrict__ dstI,
    int* __restrict__ cursor, bf16* __restrict__ eap,
    int* __restrict__ srcp, int* __restrict__ dstp) {
  int e = blockIdx.x * 256 + threadIdx.x;
  if (e >= NE) return;
  int d = dstI[e];
  int pos = atomicAdd(&cursor[d], 1);
  srcp[pos] = srcI[e];
  dstp[pos] = d;
  #pragma unroll
  for (int k = 0; k < 7; ++k) eap[(size_t)pos * 7 + k] = __float2bfloat16(ea[(size_t)e * 7 + k]);
}

// ---------------------------------------------------------------------------
// Fused edge weights: W3p[l] = ee_w2 @ W3[l], c3[l] = ee_b2 @ W3[l] + eb[l]
// ---------------------------------------------------------------------------
__global__ __launch_bounds__(256) void fuse_w3_kernel(
    const float* __restrict__ ee_w2, const float* __restrict__ ee_b2,
    const float* __restrict__ mp_ew, const float* __restrict__ mp_eb,
    float* __restrict__ W3p, float* __restrict__ c3)
{
  const int l = blockIdx.x >> 3;
  const int cc = (blockIdx.x & 7) * 16;
  __shared__ float sA[H * H];
  __shared__ float sB[H * 16];
  const float* W3 = mp_ew + (size_t)l * 384 * H + 256 * H;
  for (int i = threadIdx.x; i < H * H; i += 256) sA[i] = ee_w2[i];
  for (int i = threadIdx.x; i < H * 16; i += 256) {
    int k = i >> 4, j = i & 15;
    sB[i] = W3[k * H + cc + j];
  }
  __syncthreads();
  float* out = W3p + (size_t)l * H * H;
  for (int i = threadIdx.x; i < H * 16; i += 256) {
    int r = i >> 4, j = i & 15;
    float acc = 0.f;
    #pragma unroll 8
    for (int k = 0; k < H; ++k) acc += sA[r * H + k] * sB[k * 16 + j];
    out[r * H + cc + j] = acc;
  }
  if (threadIdx.x < 16) {
    int j = threadIdx.x;
    float acc = mp_eb[l * H + cc + j];
    for (int k = 0; k < H; ++k) acc += ee_b2[k] * sB[k * 16 + j];
    c3[l * H + cc + j] = acc;
  }
}

// ---------------------------------------------------------------------------
// Generic repack: [K x 128] f32 row-major -> bf16 MFMA B-fragment order.
// ---------------------------------------------------------------------------
__global__ __launch_bounds__(256) void repack_w_kernel(
    const float* __restrict__ src0, size_t lstride, bf16* __restrict__ dst0, int K)
{
  const int l = blockIdx.x;
  const float* src = src0 + (size_t)l * lstride;
  bf16* dst = dst0 + (size_t)l * K * 128;
  const int nkk = K / 32;
  const int nslots = 8 * nkk * 64;
  for (int idx = threadIdx.x; idx < nslots; idx += 256) {
    int ng = idx / (nkk * 64);
    int rem = idx % (nkk * 64);
    int kk = rem / 64, ln = rem % 64;
    #pragma unroll
    for (int j = 0; j < 8; ++j) {
      int k = kk * 32 + ((ln >> 4) * 8) + j;
      int col = ng * 16 + (ln & 15);
      dst[(size_t)idx * 8 + j] = __float2bfloat16(src[(size_t)k * 128 + col]);
    }
  }
}

// ---------------------------------------------------------------------------
// Node encoder: h = relu(x @ w1 + b1) @ w2 + b2   (10 -> 128 -> 128)
// ---------------------------------------------------------------------------
__global__ __launch_bounds__(256) void node_encoder_kernel(
    const float* __restrict__ in,
    const float* __restrict__ w1, const float* __restrict__ b1,
    const float* __restrict__ w2, const float* __restrict__ b2,
    float* __restrict__ out, int nrows)
{
  __shared__ float sw1[10 * H];
  __shared__ float sw2[H * H];
  __shared__ float sb1[H];
  __shared__ float sb2[H];
  __shared__ float sin_[8][10];
  __shared__ float st[8][H];

  for (int i = threadIdx.x; i < 10 * H; i += 256) sw1[i] = w1[i];
  for (int i = threadIdx.x; i < H * H; i += 256) sw2[i] = w2[i];
  if (threadIdx.x < H) { sb1[threadIdx.x] = b1[threadIdx.x]; sb2[threadIdx.x] = b2[threadIdx.x]; }
  __syncthreads();

  const int c = threadIdx.x & 127;
  const int hf = threadIdx.x >> 7;

  for (long long r0 = (long long)blockIdx.x * 8; r0 < nrows; r0 += (long long)gridDim.x * 8) {
    if (threadIdx.x < 80) {
      int j = threadIdx.x / 10, k = threadIdx.x % 10;
      long long r = r0 + j;
      sin_[j][k] = (r < nrows) ? in[r * 10 + k] : 0.f;
    }
    __syncthreads();
    #pragma unroll
    for (int t = 0; t < 4; ++t) {
      int idx = threadIdx.x + t * 256;
      int j = idx >> 7, k = idx & 127;
      float acc = sb1[k];
      #pragma unroll
      for (int i = 0; i < 10; ++i) acc += sin_[j][i] * sw1[i * H + k];
      st[j][k] = fmaxf(acc, 0.f);
    }
    __syncthreads();
    float a0 = sb2[c], a1 = a0, a2 = a0, a3 = a0;
    #pragma unroll 4
    for (int k4 = 0; k4 < H; k4 += 4) {
      float w0 = sw2[(k4 + 0) * H + c];
      float w1v = sw2[(k4 + 1) * H + c];
      float w2v = sw2[(k4 + 2) * H + c];
      float w3v = sw2[(k4 + 3) * H + c];
      float4 s0 = *(const float4*)&st[hf * 4 + 0][k4];
      float4 s1 = *(const float4*)&st[hf * 4 + 1][k4];
      float4 s2 = *(const float4*)&st[hf * 4 + 2][k4];
      float4 s3 = *(const float4*)&st[hf * 4 + 3][k4];
      a0 += s0.x * w0 + s0.y * w1v + s0.z * w2v + s0.w * w3v;
      a1 += s1.x * w0 + s1.y * w1v + s1.z * w2v + s1.w * w3v;
      a2 += s2.x * w0 + s2.y * w1v + s2.z * w2v + s2.w * w3v;
      a3 += s3.x * w0 + s3.y * w1v + s3.z * w2v + s3.w * w3v;
    }
    float accs[4] = {a0, a1, a2, a3};
    #pragma unroll
    for (int j = 0; j < 4; ++j) {
      long long r = r0 + hf * 4 + j;
      if (r < nrows) out[r * H + c] = accs[j];
    }
    __syncthreads();
  }
}

// ---------------------------------------------------------------------------
// Layer-0 node GEMMs (fp32): A = bf16(h @ W1), B = bf16(h @ W2); zeroes agg.
// ---------------------------------------------------------------------------
__global__ __launch_bounds__(512) void node_AB_kernel(
    const float* __restrict__ h, const float* __restrict__ W1f, const float* __restrict__ W2f,
    bf16* __restrict__ A, bf16* __restrict__ B, float* __restrict__ agg, int nrows)
{
  __shared__ float sw1[H * H];
  __shared__ float sw2[H * H];
  __shared__ float sh[16][H];
  for (int i = threadIdx.x; i < H * H; i += 512) { sw1[i] = W1f[i]; sw2[i] = W2f[i]; }
  __syncthreads();
  const int c = threadIdx.x & 127;
  const int q = threadIdx.x >> 7;
  for (long long r0 = (long long)blockIdx.x * 16; r0 < nrows; r0 += (long long)gridDim.x * 16) {
    #pragma unroll
    for (int t = 0; t < 4; ++t) {
      int idx = threadIdx.x + t * 512;
      int j = idx >> 7, k = idx & 127;
      long long r = r0 + j;
      sh[j][k] = (r < nrows) ? h[r * H + k] : 0.f;
    }
    __syncthreads();
    float aA[4] = {0, 0, 0, 0}, aB[4] = {0, 0, 0, 0};
    #pragma unroll 2
    for (int k4 = 0; k4 < H; k4 += 4) {
      float w10 = sw1[(k4 + 0) * H + c], w11 = sw1[(k4 + 1) * H + c];
      float w12 = sw1[(k4 + 2) * H + c], w13 = sw1[(k4 + 3) * H + c];
      float w20 = sw2[(k4 + 0) * H + c], w21 = sw2[(k4 + 1) * H + c];
      float w22 = sw2[(k4 + 2) * H + c], w23 = sw2[(k4 + 3) * H + c];
      #pragma unroll
      for (int j = 0; j < 4; ++j) {
        float4 s = *(const float4*)&sh[q * 4 + j][k4];
        aA[j] += s.x * w10 + s.y * w11 + s.z * w12 + s.w * w13;
        aB[j] += s.x * w20 + s.y * w21 + s.z * w22 + s.w * w23;
      }
    }
    #pragma unroll
    for (int j = 0; j < 4; ++j) {
      long long r = r0 + q * 4 + j;
      if (r < nrows) {
        A[r * H + c] = __float2bfloat16(aA[j]);
        B[r * H + c] = __float2bfloat16(aB[j]);
        agg[r * H + c] = 0.f;
      }
    }
    __syncthreads();
  }
}

// ---------------------------------------------------------------------------
// Edge kernel (r12 structure + LDS-only barriers in the tile loop: global
// prefetch loads and epilogue atomics stay in flight across barriers).
// ---------------------------------------------------------------------------
__global__ __launch_bounds__(512) void edge_mfma_scatter(
    const bf16* __restrict__ eap,
    const int* __restrict__ srcp, const int* __restrict__ dstp,
    const bf16* __restrict__ A, const bf16* __restrict__ B,
    const float* __restrict__ ew1, const float* __restrict__ eb1,
    const bf16* __restrict__ W3b, const float* __restrict__ c3,
    float* __restrict__ agg, int nE)
{
  __shared__ float sew1[7 * H];           // 3.5 KB
  __shared__ float seb1[H];               // 0.5 KB
  __shared__ float sea[64][8];            // 2 KB
  __shared__ int   didx[64];
  __shared__ unsigned int shid[64 * 64];  // 16 KB, bf16x2 swizzled
  __shared__ bf16  sAld[64][136];         // 17 KB staged A rows (+8 pad)

  for (int i = threadIdx.x; i < 7 * H; i += 512) sew1[i] = ew1[i];
  if (threadIdx.x < H) seb1[threadIdx.x] = eb1[threadIdx.x];

  const int t = threadIdx.x;
  const int lane = t & 63;
  const int wid = t >> 6;                 // 0..7
  const int hm = wid >> 2;                // row half
  const int colbase = (wid & 3) * 32;     // col slice

  short8v bfrag[2][4];
  float c3v[2];
  #pragma unroll
  for (int n = 0; n < 2; ++n) {
    c3v[n] = c3[colbase + n * 16 + (lane & 15)];
    int ng = (colbase >> 4) + n;
    #pragma unroll
    for (int kk = 0; kk < 4; ++kk) {
      const bf16* p = W3b + ((size_t)(ng * 4 + kk) * 64 + lane) * 8;
      bfrag[n][kk] = *(const short8v*)p;
    }
  }
  __syncthreads();

  const long long stride = (long long)gridDim.x * 64;
  const int elA0 = t >> 4;
  const int elA1 = 32 + (t >> 4);
  const int segA = (t & 15) * 8;

  // ---- prologue prefetch ----
  float   pf_ea = 0.f;
  int     pf_d = 0;
  short8v pf_A0, pf_A1;
  long long e0 = (long long)blockIdx.x * 64;
  if (e0 < nE) {
    if (t < 448) pf_ea = __bfloat162float(eap[e0 * 7 + t]);
    if (t < 64)  pf_d = dstp[e0 + t];
    int s0 = srcp[e0 + elA0];
    pf_A0 = *(const short8v*)&A[(size_t)s0 * H + segA];
    int s1 = srcp[e0 + elA1];
    pf_A1 = *(const short8v*)&A[(size_t)s1 * H + segA];
  }

  for (; e0 < nE; e0 += stride) {
    if (t < 448) sea[t / 7][t % 7] = pf_ea;
    if (t < 64)  didx[t] = pf_d;
    *(short8v*)&sAld[elA0][segA] = pf_A0;
    *(short8v*)&sAld[elA1][segA] = pf_A1;
    lds_barrier();

    long long e1 = e0 + stride;
    if (e1 < nE) {
      if (t < 448) pf_ea = __bfloat162float(eap[e1 * 7 + t]);
      if (t < 64)  pf_d = dstp[e1 + t];
      int s0 = srcp[e1 + elA0];
      pf_A0 = *(const short8v*)&A[(size_t)s0 * H + segA];
      int s1 = srcp[e1 + elA1];
      pf_A1 = *(const short8v*)&A[(size_t)s1 * H + segA];
    }

    // ---- hidden layer ----
    {
      const int e = t >> 3;
      float r0 = sea[e][0], r1 = sea[e][1], r2 = sea[e][2], r3 = sea[e][3];
      float r4 = sea[e][4], r5 = sea[e][5], r6 = sea[e][6];
      #pragma unroll
      for (int p = 0; p < 8; ++p) {
        int k2 = (t & 7) + 8 * p;
        int k = k2 * 2;
        float a0 = seb1[k], a1 = seb1[k + 1];
        a0 += r0 * sew1[0 * H + k] + r1 * sew1[1 * H + k] + r2 * sew1[2 * H + k]
            + r3 * sew1[3 * H + k] + r4 * sew1[4 * H + k] + r5 * sew1[5 * H + k]
            + r6 * sew1[6 * H + k];
        a1 += r0 * sew1[0 * H + k + 1] + r1 * sew1[1 * H + k + 1] + r2 * sew1[2 * H + k + 1]
            + r3 * sew1[3 * H + k + 1] + r4 * sew1[4 * H + k + 1] + r5 * sew1[5 * H + k + 1]
            + r6 * sew1[6 * H + k + 1];
        a0 = fmaxf(a0, 0.f); a1 = fmaxf(a1, 0.f);
        unsigned int w = (unsigned int)f2bf_bits(a0) | ((unsigned int)f2bf_bits(a1) << 16);
        int off = (e * 256 + k2 * 4) ^ ((e & 7) << 4);
        shid[off >> 2] = w;
      }
    }
    lds_barrier();

    // ---- GEMM2 ----
    f32x4 acc[2][2];
    const f32x4 z = {0.f, 0.f, 0.f, 0.f};
    acc[0][0] = z; acc[0][1] = z; acc[1][0] = z; acc[1][1] = z;
    #pragma unroll
    for (int m = 0; m < 2; ++m) {
      #pragma unroll
      for (int kk = 0; kk < 4; ++kk) {
        int row = hm * 32 + m * 16 + (lane & 15);
        int off = (row * 256 + kk * 64 + (lane >> 4) * 16) ^ ((row & 7) << 4);
        short8v afrag = *(const short8v*)((const char*)shid + off);
        acc[m][0] = __builtin_amdgcn_mfma_f32_16x16x32_bf16(afrag, bfrag[0][kk], acc[m][0], 0, 0, 0);
        acc[m][1] = __builtin_amdgcn_mfma_f32_16x16x32_bf16(afrag, bfrag[1][kk], acc[m][1], 0, 0, 0);
      }
    }

    // ---- epilogue: run-length reduce equal-dst rows, atomic ----
    const int col0 = colbase + (lane & 15);
    const int col1 = col0 + 16;
    #pragma unroll
    for (int m = 0; m < 2; ++m) {
      float vs0 = 0.f, vs1 = 0.f;
      float b0 = 0.f, b1 = 0.f;
      int dprev = -1;
      #pragma unroll
      for (int r = 0; r < 4; ++r) {
        int el = hm * 32 + m * 16 + (lane >> 4) * 4 + r;
        int d = didx[el];
        if (d != dprev) {
          if (dprev >= 0) {
            atomicAdd(&agg[(size_t)dprev * H + col0], vs0);
            atomicAdd(&agg[(size_t)dprev * H + col1], vs1);
          }
          vs0 = 0.f; vs1 = 0.f;
          b0 = __bfloat162float(B[(size_t)d * H + col0]);
          b1 = __bfloat162float(B[(size_t)d * H + col1]);
          dprev = d;
        }
        float a0v = __bfloat162float(sAld[el][col0]);
        float a1v = __bfloat162float(sAld[el][col1]);
        vs0 += fmaxf(acc[m][0][r] + c3v[0] + a0v + b0, 0.f);
        vs1 += fmaxf(acc[m][1][r] + c3v[1] + a1v + b1, 0.f);
      }
      atomicAdd(&agg[(size_t)dprev * H + col0], vs0);
      atomicAdd(&agg[(size_t)dprev * H + col1], vs1);
    }
    lds_barrier();
  }
}

// ---------------------------------------------------------------------------
// Fused node update (MFMA):
//   h' = h + relu([h|agg] @ Wn + nb)          (K=256)
//   if DO_AB: A = bf16(h' @ W1next), B = bf16(h' @ W2next), agg = 0
// Grid 521 = exactly 3 tiles/block (weight-fragment amortization).
// ---------------------------------------------------------------------------
template<int DO_AB>
__global__ __launch_bounds__(256) void fused_update_kernel(
    float* __restrict__ h, const float* __restrict__ aggin,
    const bf16* __restrict__ Wnb, const float* __restrict__ nb,
    const bf16* __restrict__ W1b, const bf16* __restrict__ W2b,
    bf16* __restrict__ A, bf16* __restrict__ B, float* __restrict__ aggz,
    int nrows)
{
  __shared__ unsigned int sKw[32 * 128];
  unsigned short* shnew = (unsigned short*)sKw;

  const int t = threadIdx.x;
  const int lane = t & 63;
  const int wid = t >> 6;
  const int colbase = wid * 32;

  short8v bU[2][8];
  float nbv[2];
  #pragma unroll
  for (int n = 0; n < 2; ++n) {
    int ng = wid * 2 + n;
    nbv[n] = nb[colbase + n * 16 + (lane & 15)];
    #pragma unroll
    for (int kk = 0; kk < 8; ++kk)
      bU[n][kk] = *(const short8v*)(Wnb + ((size_t)(ng * 8 + kk) * 64 + lane) * 8);
  }
  short8v bA[2][4], bB[2][4];
  if (DO_AB) {
    #pragma unroll
    for (int n = 0; n < 2; ++n) {
      int ng = wid * 2 + n;
      #pragma unroll
      for (int kk = 0; kk < 4; ++kk) {
        bA[n][kk] = *(const short8v*)(W1b + ((size_t)(ng * 4 + kk) * 64 + lane) * 8);
        bB[n][kk] = *(const short8v*)(W2b + ((size_t)(ng * 4 + kk) * 64 + lane) * 8);
      }
    }
  }

  const int ntiles = (nrows + 31) / 32;
  for (int tile = blockIdx.x; tile < ntiles; tile += gridDim.x) {
    const int r0 = tile * 32;
    #pragma unroll
    for (int i = 0; i < 16; ++i) {
      int w = t + i * 256;
      int row = w >> 7, k2 = w & 127;
      int r = r0 + row;
      float v0 = 0.f, v1 = 0.f;
      if (r < nrows) {
        if (k2 < 64) { float2 p = *(const float2*)&h[(size_t)r * H + 2 * k2]; v0 = p.x; v1 = p.y; }
        else         { float2 p = *(const float2*)&aggin[(size_t)r * H + 2 * k2 - 128]; v0 = p.x; v1 = p.y; }
      }
      unsigned int wrd = (unsigned int)f2bf_bits(v0) | ((unsigned int)f2bf_bits(v1) << 16);
      sKw[((w * 4) ^ ((row & 7) << 4)) >> 2] = wrd;
    }
    __syncthreads();

    f32x4 acc[2][2];
    const f32x4 z = {0.f, 0.f, 0.f, 0.f};
    acc[0][0] = z; acc[0][1] = z; acc[1][0] = z; acc[1][1] = z;
    #pragma unroll
    for (int kk = 0; kk < 8; ++kk) {
      #pragma unroll
      for (int m = 0; m < 2; ++m) {
        int row = m * 16 + (lane & 15);
        int off = (row * 512 + kk * 64 + (lane >> 4) * 16) ^ ((row & 7) << 4);
        short8v afrag = *(const short8v*)((const char*)sKw + off);
        acc[m][0] = __builtin_amdgcn_mfma_f32_16x16x32_bf16(afrag, bU[0][kk], acc[m][0], 0, 0, 0);
        acc[m][1] = __builtin_amdgcn_mfma_f32_16x16x32_bf16(afrag, bU[1][kk], acc[m][1], 0, 0, 0);
      }
    }
    __syncthreads();

    #pragma unroll
    for (int m = 0; m < 2; ++m) {
      #pragma unroll
      for (int r = 0; r < 4; ++r) {
        int row = m * 16 + (lane >> 4) * 4 + r;
        int grow = r0 + row;
        #pragma unroll
        for (int n = 0; n < 2; ++n) {
          int col = colbase + n * 16 + (lane & 15);
          float u = fmaxf(acc[m][n][r] + nbv[n], 0.f);
          float hold = (grow < nrows) ? h[(size_t)grow * H + col] : 0.f;
          float hn = hold + u;
          if (grow < nrows) h[(size_t)grow * H + col] = hn;
          if (DO_AB) {
            int i16 = (row * 128 + col) ^ ((row & 7) << 3);
            shnew[i16] = f2bf_bits(hn);
          }
        }
      }
    }

    if (DO_AB) {
      __syncthreads();
      f32x4 aA[2][2], aB2[2][2];
      aA[0][0] = z; aA[0][1] = z; aA[1][0] = z; aA[1][1] = z;
      aB2[0][0] = z; aB2[0][1] = z; aB2[1][0] = z; aB2[1][1] = z;
      #pragma unroll
      for (int kk = 0; kk < 4; ++kk) {
        #pragma unroll
        for (int m = 0; m < 2; ++m) {
          int row = m * 16 + (lane & 15);
          int off = (row * 256 + kk * 64 + (lane >> 4) * 16) ^ ((row & 7) << 4);
          short8v afrag = *(const short8v*)((const char*)shnew + off);
          aA[m][0] = __builtin_amdgcn_mfma_f32_16x16x32_bf16(afrag, bA[0][kk], aA[m][0], 0, 0, 0);
          aA[m][1] = __builtin_amdgcn_mfma_f32_16x16x32_bf16(afrag, bA[1][kk], aA[m][1], 0, 0, 0);
          aB2[m][0] = __builtin_amdgcn_mfma_f32_16x16x32_bf16(afrag, bB[0][kk], aB2[m][0], 0, 0, 0);
          aB2[m][1] = __builtin_amdgcn_mfma_f32_16x16x32_bf16(afrag, bB[1][kk], aB2[m][1], 0, 0, 0);
        }
      }
      #pragma unroll
      for (int m = 0; m < 2; ++m) {
        #pragma unroll
        for (int r = 0; r < 4; ++r) {
          int row = m * 16 + (lane >> 4) * 4 + r;
          int grow = r0 + row;
          if (grow < nrows) {
            #pragma unroll
            for (int n = 0; n < 2; ++n) {
              int col = colbase + n * 16 + (lane & 15);
              A[(size_t)grow * H + col] = __float2bfloat16(aA[m][n][r]);
              B[(size_t)grow * H + col] = __float2bfloat16(aB2[m][n][r]);
              aggz[(size_t)grow * H + col] = 0.f;
            }
          }
        }
      }
    }
    __syncthreads();
  }
}

// ---------------------------------------------------------------------------
// Decoder: pred = relu(relu(h@w1+b1)@w2+b2)@w3+b3, then BC mask.
// ---------------------------------------------------------------------------
__global__ __launch_bounds__(512) void decoder_kernel(
    const float* __restrict__ h,
    const float* __restrict__ w1, const float* __restrict__ b1,
    const float* __restrict__ w2, const float* __restrict__ b2,
    const float* __restrict__ w3, const float* __restrict__ b3,
    const float* __restrict__ bcd, const float* __restrict__ bcr,
    float* __restrict__ out, int nrows)
{
  __shared__ float sw1[H * H];
  __shared__ float sw2[H * 64];
  __shared__ float sw3[64 * 3];
  __shared__ float sb1[H], sb2[64], sb3[3];
  __shared__ float sh[16][H], st1[16][H], st2[16][64];
  for (int i = threadIdx.x; i < H * H; i += 512) sw1[i] = w1[i];
  for (int i = threadIdx.x; i < H * 64; i += 512) sw2[i] = w2[i];
  if (threadIdx.x < 64 * 3) sw3[threadIdx.x] = w3[threadIdx.x];
  if (threadIdx.x < H) sb1[threadIdx.x] = b1[threadIdx.x];
  if (threadIdx.x < 64) sb2[threadIdx.x] = b2[threadIdx.x];
  if (threadIdx.x < 3) sb3[threadIdx.x] = b3[threadIdx.x];
  __syncthreads();
  for (long long r0 = (long long)blockIdx.x * 16; r0 < nrows; r0 += (long long)gridDim.x * 16) {
    #pragma unroll
    for (int t = 0; t < 4; ++t) {
      int idx = threadIdx.x + t * 512;
      int j = idx >> 7, k = idx & 127;
      long long r = r0 + j;
      sh[j][k] = (r < nrows) ? h[r * H + k] : 0.f;
    }
    __syncthreads();
    #pragma unroll
    for (int t = 0; t < 4; ++t) {
      int idx = threadIdx.x + t * 512;
      int j = idx >> 7, k = idx & 127;
      float acc = sb1[k];
      #pragma unroll 8
      for (int i = 0; i < H; ++i) acc += sh[j][i] * sw1[i * H + k];
      st1[j][k] = fmaxf(acc, 0.f);
    }
    __syncthreads();
    #pragma unroll
    for (int t = 0; t < 2; ++t) {
      int idx = threadIdx.x + t * 512;
      int j = idx >> 6, k = idx & 63;
      float acc = sb2[k];
      #pragma unroll 8
      for (int i = 0; i < H; ++i) acc += st1[j][i] * sw2[i * 64 + k];
      st2[j][k] = fmaxf(acc, 0.f);
    }
    __syncthreads();
    if (threadIdx.x < 48) {
      int j = threadIdx.x / 3, o = threadIdx.x % 3;
      float acc = sb3[o];
      #pragma unroll 8
      for (int i = 0; i < 64; ++i) acc += st2[j][i] * sw3[i * 3 + o];
      long long r = r0 + j;
      if (r < nrows) {
        float m = (o < 2) ? (1.f - bcd[r]) : (1.f - bcr[r]);
        out[r * 3 + o] = acc * m;
      }
    }
    __syncthreads();
  }
}

extern "C" void kernel_launch(void* const* d_in, const int* in_sizes, int n_in,
                              void* d_out, int out_size, void* d_ws, size_t ws_size,
                              hipStream_t stream) {
  const float* x     = (const float*)d_in[0];
  const float* ea    = (const float*)d_in[1];
  const int*   eidx  = (const int*)d_in[2];
  const float* bcd   = (const float*)d_in[3];
  const float* bcr   = (const float*)d_in[4];
  const float* ne_w1 = (const float*)d_in[5];
  const float* ne_b1 = (const float*)d_in[6];
  const float* ne_w2 = (const float*)d_in[7];
  const float* ne_b2 = (const float*)d_in[8];
  const float* ee_w1 = (const float*)d_in[9];
  const float* ee_b1 = (const float*)d_in[10];
  const float* ee_w2 = (const float*)d_in[11];
  const float* ee_b2 = (const float*)d_in[12];
  const float* mp_ew = (const float*)d_in[13];
  const float* mp_eb = (const float*)d_in[14];
  const float* mp_nw = (const float*)d_in[15];
  const float* mp_nb = (const float*)d_in[16];
  const float* d_w1  = (const float*)d_in[17];
  const float* d_b1  = (const float*)d_in[18];
  const float* d_w2  = (const float*)d_in[19];
  const float* d_b2  = (const float*)d_in[20];
  const float* d_w3  = (const float*)d_in[21];
  const float* d_b3  = (const float*)d_in[22];

  const int* srcI = eidx;           // edge_index[0]
  const int* dstI = eidx + NE;      // edge_index[1]

  // workspace (~95.4 MB, fits 100 MiB)
  char* wsp = (char*)d_ws;
  float* h    = (float*)wsp; wsp += (size_t)NN * H * 4;          // 25.6 MB
  float* agg  = (float*)wsp; wsp += (size_t)NN * H * 4;          // 25.6 MB
  bf16*  A    = (bf16*)wsp;  wsp += (size_t)NN * H * 2;          // 12.8 MB
  bf16*  B    = (bf16*)wsp;  wsp += (size_t)NN * H * 2;          // 12.8 MB
  bf16*  eap  = (bf16*)wsp;  wsp += (size_t)NE * 7 * 2;          // 11.2 MB
  int*   srcp = (int*)wsp;   wsp += (size_t)NE * 4;              // 3.2 MB
  int*   dstp = (int*)wsp;   wsp += (size_t)NE * 4;              // 3.2 MB
  bf16*  W3b  = (bf16*)wsp;  wsp += (size_t)6 * H * H * 2;       // 0.20 MB
  bf16*  Wnb  = (bf16*)wsp;  wsp += (size_t)6 * 256 * H * 2;     // 0.39 MB
  bf16*  W1b  = (bf16*)wsp;  wsp += (size_t)6 * H * H * 2;       // 0.20 MB
  bf16*  W2b  = (bf16*)wsp;  wsp += (size_t)6 * H * H * 2;       // 0.20 MB
  float* c3   = (float*)wsp; wsp += (size_t)6 * H * 4;           // 3 KB
  int*   bsum = (int*)wsp;   wsp += 256 * 4;                     // scan partials
  // setup-time aliases (dead before their hosts are first written):
  int*   counts = (int*)A;
  int*   cursor = (int*)A + NN;
  float* W3p    = agg;

  // ---- dst-sort build (once; reused across all 6 layers) ----
  zero_counts_kernel<<<(NN + 255) / 256, 256, 0, stream>>>(counts);
  hist_kernel<<<(NE + 255) / 256, 256, 0, stream>>>(dstI, counts);
  scan1_kernel<<<NBLK, 256, 0, stream>>>(counts, bsum);
  scan2_kernel<<<1, 256, 0, stream>>>(bsum);
  scan3_kernel<<<NBLK, 256, 0, stream>>>(counts, bsum, cursor);
  scatter_kernel<<<(NE + 255) / 256, 256, 0, stream>>>(ea, srcI, dstI, cursor, eap, srcp, dstp);

  // ---- weight prep (one-time) ----
  fuse_w3_kernel<<<48, 256, 0, stream>>>(ee_w2, ee_b2, mp_ew, mp_eb, W3p, c3);
  repack_w_kernel<<<6, 256, 0, stream>>>(W3p, (size_t)H * H, W3b, 128);
  repack_w_kernel<<<6, 256, 0, stream>>>(mp_nw, (size_t)256 * H, Wnb, 256);
  repack_w_kernel<<<6, 256, 0, stream>>>(mp_ew, (size_t)384 * H, W1b, 128);
  repack_w_kernel<<<6, 256, 0, stream>>>(mp_ew + 128 * H, (size_t)384 * H, W2b, 128);

  node_encoder_kernel<<<2048, 256, 0, stream>>>(x, ne_w1, ne_b1, ne_w2, ne_b2, h, NN);
  node_AB_kernel<<<1024, 512, 0, stream>>>(h, mp_ew, mp_ew + 128 * H, A, B, agg, NN);

  for (int l = 0; l < 6; ++l) {
    // grid 6250: 800000/64 = 12500 tiles -> exactly 2 tiles/block
    edge_mfma_scatter<<<6250, 512, 0, stream>>>(eap, srcp, dstp, A, B, ee_w1, ee_b1,
                                                W3b + (size_t)l * H * H, c3 + l * H, agg, NE);
    if (l < 5) {
      // grid 521: 1563 tiles -> exactly 3 tiles/block (weight amortization)
      fused_update_kernel<1><<<521, 256, 0, stream>>>(
          h, agg, Wnb + (size_t)l * 256 * H, mp_nb + l * H,
          W1b + (size_t)(l + 1) * H * H, W2b + (size_t)(l + 1) * H * H,
          A, B, agg, NN);
    } else {
      fused_update_kernel<0><<<521, 256, 0, stream>>>(
          h, agg, Wnb + (size_t)l * 256 * H, mp_nb + l * H,
          nullptr, nullptr, nullptr, nullptr, nullptr, NN);
    }
  }

  decoder_kernel<<<1024, 512, 0, stream>>>(h, d_w1, d_b1, d_w2, d_b2, d_w3, d_b3,
                                           bcd, bcr, (float*)d_out, NN);
}